// Round 1
// baseline (186.100 us; speedup 1.0000x reference)
//
#include <hip/hip_runtime.h>
#include <cstdint>
#include <cstddef>

#define N_NODES 4096
#define IN_DIM 256
#define HID 64
#define HEADS 8
#define OUT_DIM 64
#define ALPHA 0.2f
#define MAXDEG 64

// ---------------- CSR build: ballot-compact each row of dense adj ----------------
// 1 wave per row, 4 waves per block. float4 loads: 16 iters of 1KB/wave.
__global__ __launch_bounds__(256) void build_csr(const float* __restrict__ adj,
                                                 int* __restrict__ degs,
                                                 int* __restrict__ cols) {
    int wave = threadIdx.x >> 6;
    int lane = threadIdx.x & 63;
    int row = blockIdx.x * 4 + wave;
    if (row >= N_NODES) return;
    const float4* arow = (const float4*)(adj + (size_t)row * N_NODES);
    int base = 0;
    for (int c0 = 0; c0 < N_NODES / 4; c0 += 64) {
        float4 v = arow[c0 + lane];
        float comp[4] = {v.x, v.y, v.z, v.w};
        #pragma unroll
        for (int q = 0; q < 4; ++q) {
            bool pred = comp[q] > 0.f;
            unsigned long long mask = __ballot(pred);
            if (pred) {
                int pos = base + __popcll(mask & ((1ull << lane) - 1ull));
                if (pos < MAXDEG) cols[row * MAXDEG + pos] = (c0 + lane) * 4 + q;
            }
            base += __popcll(mask);
        }
    }
    if (lane == 0) degs[row] = base < MAXDEG ? base : MAXDEG;
}

// ---------------- GEMM1: Wh[h][n][o] = sum_f x[n][f] * W_h[h][f][o] ----------------
// block: 64 rows x 64 cols (one head), 256 threads (16x16), 4x4 per thread, K-chunk 64.
__global__ __launch_bounds__(256) void gemm1(const float* __restrict__ x,
                                             const float* __restrict__ W,
                                             float* __restrict__ Wh) {
    __shared__ float xs[64][65];
    __shared__ float ws[64][68];
    int n0 = blockIdx.x * 64;
    int h = blockIdx.y;
    int t = threadIdx.x;
    int tx = t & 15, ty = t >> 4;
    float acc[4][4] = {};
    for (int kc = 0; kc < IN_DIM; kc += 64) {
        #pragma unroll
        for (int i = 0; i < 16; ++i) {
            int e = t + i * 256;
            int r = e >> 6, k = e & 63;
            xs[r][k] = x[(size_t)(n0 + r) * IN_DIM + kc + k];
            ws[r][k] = W[(size_t)h * IN_DIM * HID + (size_t)(kc + r) * HID + k];
        }
        __syncthreads();
        #pragma unroll 8
        for (int k = 0; k < 64; ++k) {
            float a_[4], b_[4];
            #pragma unroll
            for (int i = 0; i < 4; ++i) a_[i] = xs[ty * 4 + i][k];
            #pragma unroll
            for (int j = 0; j < 4; ++j) b_[j] = ws[k][tx * 4 + j];
            #pragma unroll
            for (int i = 0; i < 4; ++i)
                #pragma unroll
                for (int j = 0; j < 4; ++j) acc[i][j] += a_[i] * b_[j];
        }
        __syncthreads();
    }
    #pragma unroll
    for (int i = 0; i < 4; ++i)
        #pragma unroll
        for (int j = 0; j < 4; ++j)
            Wh[((size_t)h * N_NODES + n0 + ty * 4 + i) * HID + tx * 4 + j] = acc[i][j];
}

// ---------------- GEMM2: Wh2[n][o] = sum_k h[n][k] * Wo[k][o], K=512 ----------------
__global__ __launch_bounds__(256) void gemm2(const float* __restrict__ hfeat,
                                             const float* __restrict__ Wo,
                                             float* __restrict__ Wh2) {
    __shared__ float xs[64][65];
    __shared__ float ws[64][68];
    int n0 = blockIdx.x * 64;
    int t = threadIdx.x;
    int tx = t & 15, ty = t >> 4;
    float acc[4][4] = {};
    for (int kc = 0; kc < HEADS * HID; kc += 64) {
        #pragma unroll
        for (int i = 0; i < 16; ++i) {
            int e = t + i * 256;
            int r = e >> 6, k = e & 63;
            xs[r][k] = hfeat[(size_t)(n0 + r) * (HEADS * HID) + kc + k];
            ws[r][k] = Wo[(size_t)(kc + r) * OUT_DIM + k];
        }
        __syncthreads();
        #pragma unroll 8
        for (int k = 0; k < 64; ++k) {
            float a_[4], b_[4];
            #pragma unroll
            for (int i = 0; i < 4; ++i) a_[i] = xs[ty * 4 + i][k];
            #pragma unroll
            for (int j = 0; j < 4; ++j) b_[j] = ws[k][tx * 4 + j];
            #pragma unroll
            for (int i = 0; i < 4; ++i)
                #pragma unroll
                for (int j = 0; j < 4; ++j) acc[i][j] += a_[i] * b_[j];
        }
        __syncthreads();
    }
    #pragma unroll
    for (int i = 0; i < 4; ++i)
        #pragma unroll
        for (int j = 0; j < 4; ++j)
            Wh2[(size_t)(n0 + ty * 4 + i) * OUT_DIM + tx * 4 + j] = acc[i][j];
}

// ---------------- f1/f2: per-(h,n) dot of Wh row with a1/a2 ----------------
// 1 wave per (h,n) pair; lane = hidden dim (HID==64==wave size).
__global__ __launch_bounds__(256) void fvec(const float* __restrict__ Wh,
                                            const float* __restrict__ a1,
                                            const float* __restrict__ a2,
                                            float* __restrict__ f1,
                                            float* __restrict__ f2,
                                            int total) {
    int wave = threadIdx.x >> 6;
    int lane = threadIdx.x & 63;
    int idx = blockIdx.x * 4 + wave;
    if (idx >= total) return;
    int h = idx >> 12;  // N==4096
    float v = Wh[(size_t)idx * HID + lane];
    float s1 = v * a1[h * HID + lane];
    float s2 = v * a2[h * HID + lane];
    #pragma unroll
    for (int off = 32; off; off >>= 1) {
        s1 += __shfl_xor(s1, off);
        s2 += __shfl_xor(s2, off);
    }
    if (lane == 0) {
        f1[idx] = s1;
        f2[idx] = s2;
    }
}

// ---------------- sparse attention: softmax over neighbors + PV gather ----------------
// 1 wave per (h,n); lane<deg holds a neighbor for softmax, then lane = output dim.
__global__ __launch_bounds__(256) void attn(const float* __restrict__ Wh,
                                            const float* __restrict__ f1,
                                            const float* __restrict__ f2,
                                            const int* __restrict__ degs,
                                            const int* __restrict__ cols,
                                            float* __restrict__ out,
                                            int ldo, int total, int applyElu) {
    int wave = threadIdx.x >> 6;
    int lane = threadIdx.x & 63;
    int idx = blockIdx.x * 4 + wave;
    if (idx >= total) return;
    int h = idx >> 12;
    int n = idx & (N_NODES - 1);
    int deg = degs[n];
    int col = 0;
    float e = -1e30f;
    if (lane < deg) {
        col = cols[n * MAXDEG + lane];
        float v = f1[idx] + f2[(h << 12) + col];
        e = v > 0.f ? v : ALPHA * v;
    }
    float m = e;
    #pragma unroll
    for (int off = 32; off; off >>= 1) m = fmaxf(m, __shfl_xor(m, off));
    float p = (lane < deg) ? expf(e - m) : 0.f;
    float s = p;
    #pragma unroll
    for (int off = 32; off; off >>= 1) s += __shfl_xor(s, off);
    float inv = 1.f / s;
    float acc = 0.f;
    for (int j = 0; j < deg; ++j) {
        int cj = __shfl(col, j);
        float pj = __shfl(p, j);
        acc += pj * Wh[((size_t)(h << 12) + cj) * HID + lane];
    }
    acc *= inv;
    if (applyElu) acc = acc > 0.f ? acc : expf(acc) - 1.f;
    out[(size_t)n * ldo + h * HID + lane] = acc;
}

extern "C" void kernel_launch(void* const* d_in, const int* in_sizes, int n_in,
                              void* d_out, int out_size, void* d_ws, size_t ws_size,
                              hipStream_t stream) {
    const float* x    = (const float*)d_in[0];
    const float* adj  = (const float*)d_in[1];
    const float* W_h  = (const float*)d_in[2];
    const float* a1_h = (const float*)d_in[3];
    const float* a2_h = (const float*)d_in[4];
    const float* W_o  = (const float*)d_in[5];
    const float* a1_o = (const float*)d_in[6];
    const float* a2_o = (const float*)d_in[7];
    float* out = (float*)d_out;

    float* wsf  = (float*)d_ws;
    float* Wh1  = wsf;                                        // 8*4096*64 = 2097152
    float* hbuf = Wh1 + (size_t)HEADS * N_NODES * HID;        // 4096*512  = 2097152
    float* Wh2  = hbuf + (size_t)N_NODES * HEADS * HID;       // 4096*64   = 262144
    float* f1_1 = Wh2 + (size_t)N_NODES * OUT_DIM;            // 32768
    float* f2_1 = f1_1 + HEADS * N_NODES;                     // 32768
    float* f1_2 = f2_1 + HEADS * N_NODES;                     // 4096
    float* f2_2 = f1_2 + N_NODES;                             // 4096
    int*   degs = (int*)(f2_2 + N_NODES);                     // 4096
    int*   csr  = degs + N_NODES;                             // 4096*64

    // 1. CSR from dense adj (shared by both layers)
    build_csr<<<N_NODES / 4, 256, 0, stream>>>(adj, degs, csr);

    // 2. Layer 1: Wh = x @ W_h  (per head)
    gemm1<<<dim3(N_NODES / 64, HEADS), 256, 0, stream>>>(x, W_h, Wh1);

    // 3. f1/f2 for layer 1
    fvec<<<(HEADS * N_NODES) / 4, 256, 0, stream>>>(Wh1, a1_h, a2_h, f1_1, f2_1, HEADS * N_NODES);

    // 4. sparse attention layer 1 -> hbuf [N][512] (heads concatenated)
    attn<<<(HEADS * N_NODES) / 4, 256, 0, stream>>>(Wh1, f1_1, f2_1, degs, csr,
                                                    hbuf, HEADS * HID, HEADS * N_NODES, 0);

    // 5. Layer 2: Wh2 = hbuf @ W_o
    gemm2<<<N_NODES / 64, 256, 0, stream>>>(hbuf, W_o, Wh2);

    // 6. f1/f2 for layer 2
    fvec<<<N_NODES / 4, 256, 0, stream>>>(Wh2, a1_o, a2_o, f1_2, f2_2, N_NODES);

    // 7. sparse attention layer 2 + ELU -> d_out [N][64]
    attn<<<N_NODES / 4, 256, 0, stream>>>(Wh2, f1_2, f2_2, degs, csr,
                                          out, OUT_DIM, N_NODES, 1);
}

// Round 2
// 93.911 us; speedup vs baseline: 1.9817x; 1.9817x over previous
//
#include <hip/hip_runtime.h>
#include <cstdint>
#include <cstddef>

#define N_NODES 4096
#define IN_DIM 256
#define HID 64
#define HEADS 8
#define OUT_DIM 64
#define ALPHA 0.2f
#define MAXDEG 64

// ---------------- CSR build: ballot-compact each row of dense adj ----------------
// 1 wave per row, 4 waves per block. float4 loads: 16 iters of 1KB/wave.
__global__ __launch_bounds__(256) void build_csr(const float* __restrict__ adj,
                                                 int* __restrict__ degs,
                                                 int* __restrict__ cols) {
    int wave = threadIdx.x >> 6;
    int lane = threadIdx.x & 63;
    int row = blockIdx.x * 4 + wave;
    if (row >= N_NODES) return;
    const float4* arow = (const float4*)(adj + (size_t)row * N_NODES);
    int base = 0;
    for (int c0 = 0; c0 < N_NODES / 4; c0 += 64) {
        float4 v = arow[c0 + lane];
        float comp[4] = {v.x, v.y, v.z, v.w};
        #pragma unroll
        for (int q = 0; q < 4; ++q) {
            bool pred = comp[q] > 0.f;
            unsigned long long mask = __ballot(pred);
            if (pred) {
                int pos = base + __popcll(mask & ((1ull << lane) - 1ull));
                if (pos < MAXDEG) cols[row * MAXDEG + pos] = (c0 + lane) * 4 + q;
            }
            base += __popcll(mask);
        }
    }
    if (lane == 0) degs[row] = base < MAXDEG ? base : MAXDEG;
}

// ---------------- GEMM1 + fused f1/f2 ----------------
// Wh[h][n][o] = sum_f x[n][f]*W_h[h][f][o]; f1[h][n] = Wh[h][n]·a1[h]; f2 likewise.
// block: 64 rows x 64 cols (one head), 256 threads (16x16), 4x4/thread, K-chunk 64.
// float4 staging; LDS rows padded to 68 floats (272B, 16B-aligned).
__global__ __launch_bounds__(256) void gemm1_f(const float* __restrict__ x,
                                               const float* __restrict__ W,
                                               const float* __restrict__ a1,
                                               const float* __restrict__ a2,
                                               float* __restrict__ Wh,
                                               float* __restrict__ f1,
                                               float* __restrict__ f2) {
    __shared__ float xs[64][68];
    __shared__ float ws[64][68];
    int n0 = blockIdx.x * 64;
    int h = blockIdx.y;
    int t = threadIdx.x;
    int tx = t & 15, ty = t >> 4;
    float acc[4][4] = {};
    const float4* x4 = (const float4*)x;
    const float4* w4 = (const float4*)(W + (size_t)h * IN_DIM * HID);
    for (int kc = 0; kc < IN_DIM; kc += 64) {
        #pragma unroll
        for (int i = 0; i < 4; ++i) {
            int e = t + i * 256;          // float4 index within 64x16
            int r = e >> 4, c4 = e & 15;
            float4 xv = x4[(size_t)(n0 + r) * (IN_DIM / 4) + (kc >> 2) + c4];
            float4 wv = w4[(size_t)(kc + r) * (HID / 4) + c4];
            *(float4*)&xs[r][c4 * 4] = xv;
            *(float4*)&ws[r][c4 * 4] = wv;
        }
        __syncthreads();
        #pragma unroll 8
        for (int k = 0; k < 64; ++k) {
            float a_[4], b_[4];
            #pragma unroll
            for (int i = 0; i < 4; ++i) a_[i] = xs[ty * 4 + i][k];   // broadcast reads
            #pragma unroll
            for (int j = 0; j < 4; ++j) b_[j] = ws[k][tx * 4 + j];   // 2-way (free)
            #pragma unroll
            for (int i = 0; i < 4; ++i)
                #pragma unroll
                for (int j = 0; j < 4; ++j) acc[i][j] += a_[i] * b_[j];
        }
        __syncthreads();
    }
    float a1v[4], a2v[4];
    #pragma unroll
    for (int j = 0; j < 4; ++j) {
        a1v[j] = a1[h * HID + tx * 4 + j];
        a2v[j] = a2[h * HID + tx * 4 + j];
    }
    #pragma unroll
    for (int i = 0; i < 4; ++i) {
        int n = n0 + ty * 4 + i;
        *(float4*)&Wh[((size_t)h * N_NODES + n) * HID + tx * 4] =
            make_float4(acc[i][0], acc[i][1], acc[i][2], acc[i][3]);
        float s1 = acc[i][0] * a1v[0] + acc[i][1] * a1v[1] + acc[i][2] * a1v[2] + acc[i][3] * a1v[3];
        float s2 = acc[i][0] * a2v[0] + acc[i][1] * a2v[1] + acc[i][2] * a2v[2] + acc[i][3] * a2v[3];
        #pragma unroll
        for (int off = 8; off; off >>= 1) {
            s1 += __shfl_xor(s1, off);   // reduce over the 16 tx lanes (lane bits 0..3)
            s2 += __shfl_xor(s2, off);
        }
        if (tx == 0) {
            f1[h * N_NODES + n] = s1;
            f2[h * N_NODES + n] = s2;
        }
    }
}

// ---------------- GEMM2 + fused f1/f2 ----------------
// Wh2[n][o] = sum_k h[n][k]*Wo[k][o], K=512. block: 32 rows x 64 cols, 128 blocks.
// 256 threads (16x16), 2x4/thread.
__global__ __launch_bounds__(256) void gemm2_f(const float* __restrict__ hfeat,
                                               const float* __restrict__ Wo,
                                               const float* __restrict__ a1,
                                               const float* __restrict__ a2,
                                               float* __restrict__ Wh2,
                                               float* __restrict__ f1,
                                               float* __restrict__ f2) {
    __shared__ float xs[32][68];
    __shared__ float ws[64][68];
    int n0 = blockIdx.x * 32;
    int t = threadIdx.x;
    int tx = t & 15, ty = t >> 4;
    float acc[2][4] = {};
    const float4* x4 = (const float4*)hfeat;
    const float4* w4 = (const float4*)Wo;
    for (int kc = 0; kc < HEADS * HID; kc += 64) {
        #pragma unroll
        for (int i = 0; i < 2; ++i) {
            int e = t + i * 256;
            int r = e >> 4, c4 = e & 15;
            *(float4*)&xs[r][c4 * 4] = x4[(size_t)(n0 + r) * (HEADS * HID / 4) + (kc >> 2) + c4];
        }
        #pragma unroll
        for (int i = 0; i < 4; ++i) {
            int e = t + i * 256;
            int r = e >> 4, c4 = e & 15;
            *(float4*)&ws[r][c4 * 4] = w4[(size_t)(kc + r) * (OUT_DIM / 4) + c4];
        }
        __syncthreads();
        #pragma unroll 8
        for (int k = 0; k < 64; ++k) {
            float b_[4];
            #pragma unroll
            for (int j = 0; j < 4; ++j) b_[j] = ws[k][tx * 4 + j];
            float a0 = xs[ty * 2][k];
            float a1r = xs[ty * 2 + 1][k];
            #pragma unroll
            for (int j = 0; j < 4; ++j) {
                acc[0][j] += a0 * b_[j];
                acc[1][j] += a1r * b_[j];
            }
        }
        __syncthreads();
    }
    float a1v[4], a2v[4];
    #pragma unroll
    for (int j = 0; j < 4; ++j) {
        a1v[j] = a1[tx * 4 + j];
        a2v[j] = a2[tx * 4 + j];
    }
    #pragma unroll
    for (int i = 0; i < 2; ++i) {
        int n = n0 + ty * 2 + i;
        *(float4*)&Wh2[(size_t)n * OUT_DIM + tx * 4] =
            make_float4(acc[i][0], acc[i][1], acc[i][2], acc[i][3]);
        float s1 = acc[i][0] * a1v[0] + acc[i][1] * a1v[1] + acc[i][2] * a1v[2] + acc[i][3] * a1v[3];
        float s2 = acc[i][0] * a2v[0] + acc[i][1] * a2v[1] + acc[i][2] * a2v[2] + acc[i][3] * a2v[3];
        #pragma unroll
        for (int off = 8; off; off >>= 1) {
            s1 += __shfl_xor(s1, off);
            s2 += __shfl_xor(s2, off);
        }
        if (tx == 0) {
            f1[n] = s1;
            f2[n] = s2;
        }
    }
}

// ---------------- sparse attention: softmax over neighbors + PV gather ----------------
// 1 wave per (h,n); lane<deg holds a neighbor for softmax, then lane = output dim.
__global__ __launch_bounds__(256) void attn(const float* __restrict__ Wh,
                                            const float* __restrict__ f1,
                                            const float* __restrict__ f2,
                                            const int* __restrict__ degs,
                                            const int* __restrict__ cols,
                                            float* __restrict__ out,
                                            int ldo, int total, int applyElu) {
    int wave = threadIdx.x >> 6;
    int lane = threadIdx.x & 63;
    int idx = blockIdx.x * 4 + wave;
    if (idx >= total) return;
    int h = idx >> 12;
    int n = idx & (N_NODES - 1);
    int deg = degs[n];
    int col = 0;
    float e = -1e30f;
    if (lane < deg) {
        col = cols[n * MAXDEG + lane];
        float v = f1[idx] + f2[(h << 12) + col];
        e = v > 0.f ? v : ALPHA * v;
    }
    float m = e;
    #pragma unroll
    for (int off = 32; off; off >>= 1) m = fmaxf(m, __shfl_xor(m, off));
    float p = (lane < deg) ? expf(e - m) : 0.f;
    float s = p;
    #pragma unroll
    for (int off = 32; off; off >>= 1) s += __shfl_xor(s, off);
    float inv = 1.f / s;
    float acc = 0.f;
    for (int j = 0; j < deg; ++j) {
        int cj = __shfl(col, j);
        float pj = __shfl(p, j);
        acc += pj * Wh[((size_t)(h << 12) + cj) * HID + lane];
    }
    acc *= inv;
    if (applyElu) acc = acc > 0.f ? acc : expf(acc) - 1.f;
    out[(size_t)n * ldo + h * HID + lane] = acc;
}

extern "C" void kernel_launch(void* const* d_in, const int* in_sizes, int n_in,
                              void* d_out, int out_size, void* d_ws, size_t ws_size,
                              hipStream_t stream) {
    const float* x    = (const float*)d_in[0];
    const float* adj  = (const float*)d_in[1];
    const float* W_h  = (const float*)d_in[2];
    const float* a1_h = (const float*)d_in[3];
    const float* a2_h = (const float*)d_in[4];
    const float* W_o  = (const float*)d_in[5];
    const float* a1_o = (const float*)d_in[6];
    const float* a2_o = (const float*)d_in[7];
    float* out = (float*)d_out;

    float* wsf  = (float*)d_ws;
    float* Wh1  = wsf;                                        // 8*4096*64
    float* hbuf = Wh1 + (size_t)HEADS * N_NODES * HID;        // 4096*512
    float* Wh2  = hbuf + (size_t)N_NODES * HEADS * HID;       // 4096*64
    float* f1_1 = Wh2 + (size_t)N_NODES * OUT_DIM;            // 32768
    float* f2_1 = f1_1 + HEADS * N_NODES;                     // 32768
    float* f1_2 = f2_1 + HEADS * N_NODES;                     // 4096
    float* f2_2 = f1_2 + N_NODES;                             // 4096
    int*   degs = (int*)(f2_2 + N_NODES);                     // 4096
    int*   csr  = degs + N_NODES;                             // 4096*64

    // 1. CSR from dense adj (shared by both layers)
    build_csr<<<N_NODES / 4, 256, 0, stream>>>(adj, degs, csr);

    // 2. Layer 1: Wh = x @ W_h (per head) + fused f1/f2
    gemm1_f<<<dim3(N_NODES / 64, HEADS), 256, 0, stream>>>(x, W_h, a1_h, a2_h, Wh1, f1_1, f2_1);

    // 3. sparse attention layer 1 -> hbuf [N][512] (heads concatenated)
    attn<<<(HEADS * N_NODES) / 4, 256, 0, stream>>>(Wh1, f1_1, f2_1, degs, csr,
                                                    hbuf, HEADS * HID, HEADS * N_NODES, 0);

    // 4. Layer 2: Wh2 = hbuf @ W_o + fused f1/f2
    gemm2_f<<<N_NODES / 32, 256, 0, stream>>>(hbuf, W_o, a1_o, a2_o, Wh2, f1_2, f2_2);

    // 5. sparse attention layer 2 + ELU -> d_out [N][64]
    attn<<<N_NODES / 4, 256, 0, stream>>>(Wh2, f1_2, f2_2, degs, csr,
                                          out, OUT_DIM, N_NODES, 1);
}

// Round 3
// 78.265 us; speedup vs baseline: 2.3778x; 1.1999x over previous
//
#include <hip/hip_runtime.h>
#include <cstdint>
#include <cstddef>

#define N_NODES 4096
#define IN_DIM 256
#define HID 64
#define HEADS 8
#define OUT_DIM 64
#define ALPHA 0.2f
#define MAXDEG 64

// ================= K1: fused {gemm1 (blocks 0..511)} || {csr build (blocks 512..1535)} =========
// gemm1: Wh[n][h][o] = sum_f x[n][f]*W_h[h][f][o]; f1[n][h] = Wh[n][h]·a1[h]; f2 likewise.
// 64x64 tile per block (one head), 256 threads (16x16), 4x4/thread, K-chunk 64.
// csr: ballot-compact 4 rows/block of the dense adjacency.
__global__ __launch_bounds__(256) void k1_gemm_csr(const float* __restrict__ x,
                                                   const float* __restrict__ W,
                                                   const float* __restrict__ a1,
                                                   const float* __restrict__ a2,
                                                   float* __restrict__ Wh,
                                                   float* __restrict__ f1,
                                                   float* __restrict__ f2,
                                                   const float* __restrict__ adj,
                                                   int* __restrict__ degs,
                                                   int* __restrict__ cols) {
    int bid = blockIdx.x;
    if (bid < 512) {
        // ---------------- GEMM1 + fused f1/f2 ----------------
        __shared__ float xs[64][68];
        __shared__ float ws[64][68];
        int h = bid & 7;
        int n0 = (bid >> 3) * 64;
        int t = threadIdx.x;
        int tx = t & 15, ty = t >> 4;
        float acc[4][4] = {};
        const float4* x4 = (const float4*)x;
        const float4* w4 = (const float4*)(W + (size_t)h * IN_DIM * HID);
        for (int kc = 0; kc < IN_DIM; kc += 64) {
            #pragma unroll
            for (int i = 0; i < 4; ++i) {
                int e = t + i * 256;
                int r = e >> 4, c4 = e & 15;
                *(float4*)&xs[r][c4 * 4] = x4[(size_t)(n0 + r) * (IN_DIM / 4) + (kc >> 2) + c4];
                *(float4*)&ws[r][c4 * 4] = w4[(size_t)(kc + r) * (HID / 4) + c4];
            }
            __syncthreads();
            #pragma unroll 8
            for (int k = 0; k < 64; ++k) {
                float4 b4 = *(const float4*)&ws[k][tx * 4];     // ds_read_b128
                float b_[4] = {b4.x, b4.y, b4.z, b4.w};
                float a_[4];
                #pragma unroll
                for (int i = 0; i < 4; ++i) a_[i] = xs[ty * 4 + i][k];  // wave-broadcast
                #pragma unroll
                for (int i = 0; i < 4; ++i)
                    #pragma unroll
                    for (int j = 0; j < 4; ++j) acc[i][j] += a_[i] * b_[j];
            }
            __syncthreads();
        }
        float a1v[4], a2v[4];
        #pragma unroll
        for (int j = 0; j < 4; ++j) {
            a1v[j] = a1[h * HID + tx * 4 + j];
            a2v[j] = a2[h * HID + tx * 4 + j];
        }
        #pragma unroll
        for (int i = 0; i < 4; ++i) {
            int n = n0 + ty * 4 + i;
            // layout: Wh[n][h][o]
            *(float4*)&Wh[((size_t)n * HEADS + h) * HID + tx * 4] =
                make_float4(acc[i][0], acc[i][1], acc[i][2], acc[i][3]);
            float s1 = acc[i][0]*a1v[0] + acc[i][1]*a1v[1] + acc[i][2]*a1v[2] + acc[i][3]*a1v[3];
            float s2 = acc[i][0]*a2v[0] + acc[i][1]*a2v[1] + acc[i][2]*a2v[2] + acc[i][3]*a2v[3];
            #pragma unroll
            for (int off = 8; off; off >>= 1) {
                s1 += __shfl_xor(s1, off);
                s2 += __shfl_xor(s2, off);
            }
            if (tx == 0) {
                f1[n * HEADS + h] = s1;   // layout: f1[n][h]
                f2[n * HEADS + h] = s2;
            }
        }
    } else {
        // ---------------- CSR build ----------------
        int wave = threadIdx.x >> 6;
        int lane = threadIdx.x & 63;
        int row = (bid - 512) * 4 + wave;
        if (row >= N_NODES) return;
        const float4* arow = (const float4*)(adj + (size_t)row * N_NODES);
        int base = 0;
        for (int c0 = 0; c0 < N_NODES / 4; c0 += 64) {
            float4 v = arow[c0 + lane];
            float comp[4] = {v.x, v.y, v.z, v.w};
            #pragma unroll
            for (int q = 0; q < 4; ++q) {
                bool pred = comp[q] > 0.f;
                unsigned long long mask = __ballot(pred);
                if (pred) {
                    int pos = base + __popcll(mask & ((1ull << lane) - 1ull));
                    if (pos < MAXDEG) cols[row * MAXDEG + pos] = (c0 + lane) * 4 + q;
                }
                base += __popcll(mask);
            }
        }
        if (lane == 0) degs[row] = base < MAXDEG ? base : MAXDEG;
    }
}

// ================= K2: attention layer 1, one block per node, all 8 heads ==================
// Wh [n][h][o], f1/f2 [n][h], out hbuf [n][512]. Gather = deg x 2KB contiguous.
__global__ __launch_bounds__(256) void attn1_node(const float* __restrict__ Wh,
                                                  const float* __restrict__ f1,
                                                  const float* __restrict__ f2,
                                                  const int* __restrict__ degs,
                                                  const int* __restrict__ cols,
                                                  float* __restrict__ out) {
    __shared__ int cols_s[MAXDEG];
    __shared__ float p_s[HEADS][MAXDEG];
    __shared__ float inv_s[HEADS];
    int n = blockIdx.x;
    int t = threadIdx.x;
    int wave = t >> 6, lane = t & 63;
    int deg = degs[n];
    if (t < deg) cols_s[t] = cols[n * MAXDEG + t];
    __syncthreads();
    // phase A: wave w -> heads w and w+4: per-head softmax over neighbors
    #pragma unroll
    for (int pass = 0; pass < 2; ++pass) {
        int h = wave + 4 * pass;
        float e = -1e30f;
        if (lane < deg) {
            int cj = cols_s[lane];
            float v = f1[n * HEADS + h] + f2[cj * HEADS + h];
            e = v > 0.f ? v : ALPHA * v;
        }
        float m = e;
        #pragma unroll
        for (int off = 32; off; off >>= 1) m = fmaxf(m, __shfl_xor(m, off));
        float p = (lane < deg) ? expf(e - m) : 0.f;
        float s = p;
        #pragma unroll
        for (int off = 32; off; off >>= 1) s += __shfl_xor(s, off);
        p_s[h][lane] = p;
        if (lane == 0) inv_s[h] = 1.f / s;
    }
    __syncthreads();
    // phase B: wave w -> heads w, w+4: PV gather (256B contiguous per (neighbor, head))
    #pragma unroll
    for (int pass = 0; pass < 2; ++pass) {
        int h = wave + 4 * pass;
        float acc = 0.f;
        for (int j = 0; j < deg; ++j) {
            acc += p_s[h][j] * Wh[((size_t)cols_s[j] * HEADS + h) * HID + lane];
        }
        out[(size_t)n * (HEADS * HID) + h * HID + lane] = acc * inv_s[h];
    }
}

// ================= K3: GEMM2 + fused f1/f2 =================
// Wh2[n][o] = sum_k h[n][k]*Wo[k][o], K=512. 32 rows x 64 cols per block, 128 blocks.
__global__ __launch_bounds__(256) void gemm2_f(const float* __restrict__ hfeat,
                                               const float* __restrict__ Wo,
                                               const float* __restrict__ a1,
                                               const float* __restrict__ a2,
                                               float* __restrict__ Wh2,
                                               float* __restrict__ f1,
                                               float* __restrict__ f2) {
    __shared__ float xs[32][68];
    __shared__ float ws[64][68];
    int n0 = blockIdx.x * 32;
    int t = threadIdx.x;
    int tx = t & 15, ty = t >> 4;
    float acc[2][4] = {};
    const float4* x4 = (const float4*)hfeat;
    const float4* w4 = (const float4*)Wo;
    for (int kc = 0; kc < HEADS * HID; kc += 64) {
        #pragma unroll
        for (int i = 0; i < 2; ++i) {
            int e = t + i * 256;
            int r = e >> 4, c4 = e & 15;
            *(float4*)&xs[r][c4 * 4] = x4[(size_t)(n0 + r) * (HEADS * HID / 4) + (kc >> 2) + c4];
        }
        #pragma unroll
        for (int i = 0; i < 4; ++i) {
            int e = t + i * 256;
            int r = e >> 4, c4 = e & 15;
            *(float4*)&ws[r][c4 * 4] = w4[(size_t)(kc + r) * (OUT_DIM / 4) + c4];
        }
        __syncthreads();
        #pragma unroll 8
        for (int k = 0; k < 64; ++k) {
            float4 b4 = *(const float4*)&ws[k][tx * 4];
            float b_[4] = {b4.x, b4.y, b4.z, b4.w};
            float a0 = xs[ty * 2][k];
            float a1r = xs[ty * 2 + 1][k];
            #pragma unroll
            for (int j = 0; j < 4; ++j) {
                acc[0][j] += a0 * b_[j];
                acc[1][j] += a1r * b_[j];
            }
        }
        __syncthreads();
    }
    float a1v[4], a2v[4];
    #pragma unroll
    for (int j = 0; j < 4; ++j) {
        a1v[j] = a1[tx * 4 + j];
        a2v[j] = a2[tx * 4 + j];
    }
    #pragma unroll
    for (int i = 0; i < 2; ++i) {
        int n = n0 + ty * 2 + i;
        *(float4*)&Wh2[(size_t)n * OUT_DIM + tx * 4] =
            make_float4(acc[i][0], acc[i][1], acc[i][2], acc[i][3]);
        float s1 = acc[i][0]*a1v[0] + acc[i][1]*a1v[1] + acc[i][2]*a1v[2] + acc[i][3]*a1v[3];
        float s2 = acc[i][0]*a2v[0] + acc[i][1]*a2v[1] + acc[i][2]*a2v[2] + acc[i][3]*a2v[3];
        #pragma unroll
        for (int off = 8; off; off >>= 1) {
            s1 += __shfl_xor(s1, off);
            s2 += __shfl_xor(s2, off);
        }
        if (tx == 0) {
            f1[n] = s1;
            f2[n] = s2;
        }
    }
}

// ================= K4: attention layer 2 (+ELU), 1 wave per node ==================
__global__ __launch_bounds__(256) void attn2(const float* __restrict__ Wh,
                                             const float* __restrict__ f1,
                                             const float* __restrict__ f2,
                                             const int* __restrict__ degs,
                                             const int* __restrict__ cols,
                                             float* __restrict__ out) {
    int wave = threadIdx.x >> 6;
    int lane = threadIdx.x & 63;
    int n = blockIdx.x * 4 + wave;
    if (n >= N_NODES) return;
    int deg = degs[n];
    int col = 0;
    float e = -1e30f;
    if (lane < deg) {
        col = cols[n * MAXDEG + lane];
        float v = f1[n] + f2[col];
        e = v > 0.f ? v : ALPHA * v;
    }
    float m = e;
    #pragma unroll
    for (int off = 32; off; off >>= 1) m = fmaxf(m, __shfl_xor(m, off));
    float p = (lane < deg) ? expf(e - m) : 0.f;
    float s = p;
    #pragma unroll
    for (int off = 32; off; off >>= 1) s += __shfl_xor(s, off);
    float inv = 1.f / s;
    float acc = 0.f;
    for (int j = 0; j < deg; ++j) {
        int cj = __shfl(col, j);
        float pj = __shfl(p, j);
        acc += pj * Wh[(size_t)cj * OUT_DIM + lane];
    }
    acc *= inv;
    acc = acc > 0.f ? acc : expf(acc) - 1.f;   // ELU
    out[(size_t)n * OUT_DIM + lane] = acc;
}

extern "C" void kernel_launch(void* const* d_in, const int* in_sizes, int n_in,
                              void* d_out, int out_size, void* d_ws, size_t ws_size,
                              hipStream_t stream) {
    const float* x    = (const float*)d_in[0];
    const float* adj  = (const float*)d_in[1];
    const float* W_h  = (const float*)d_in[2];
    const float* a1_h = (const float*)d_in[3];
    const float* a2_h = (const float*)d_in[4];
    const float* W_o  = (const float*)d_in[5];
    const float* a1_o = (const float*)d_in[6];
    const float* a2_o = (const float*)d_in[7];
    float* out = (float*)d_out;

    float* wsf  = (float*)d_ws;
    float* Wh1  = wsf;                                        // [n][h][o] 8*4096*64
    float* hbuf = Wh1 + (size_t)HEADS * N_NODES * HID;        // [n][512]
    float* Wh2  = hbuf + (size_t)N_NODES * HEADS * HID;       // [n][64]
    float* f1_1 = Wh2 + (size_t)N_NODES * OUT_DIM;            // [n][8]
    float* f2_1 = f1_1 + HEADS * N_NODES;                     // [n][8]
    float* f1_2 = f2_1 + HEADS * N_NODES;                     // [n]
    float* f2_2 = f1_2 + N_NODES;                             // [n]
    int*   degs = (int*)(f2_2 + N_NODES);                     // [n]
    int*   csr  = degs + N_NODES;                             // [n][64]

    // K1: gemm1+f (512 blocks) || csr build (1024 blocks)
    k1_gemm_csr<<<512 + N_NODES / 4, 256, 0, stream>>>(x, W_h, a1_h, a2_h, Wh1, f1_1, f2_1,
                                                       adj, degs, csr);

    // K2: attention layer 1 -> hbuf [n][512]
    attn1_node<<<N_NODES, 256, 0, stream>>>(Wh1, f1_1, f2_1, degs, csr, hbuf);

    // K3: layer 2 GEMM + fused f1/f2
    gemm2_f<<<N_NODES / 32, 256, 0, stream>>>(hbuf, W_o, a1_o, a2_o, Wh2, f1_2, f2_2);

    // K4: attention layer 2 + ELU -> d_out [n][64]
    attn2<<<N_NODES / 4, 256, 0, stream>>>(Wh2, f1_2, f2_2, degs, csr, out);
}

// Round 4
// 68.107 us; speedup vs baseline: 2.7325x; 1.1491x over previous
//
#include <hip/hip_runtime.h>
#include <cstdint>
#include <cstddef>

#define N_NODES 4096
#define IN_DIM 256
#define HID 64
#define HEADS 8
#define OUT_DIM 64
#define ALPHA 0.2f
#define MAXDEG 64

typedef __attribute__((ext_vector_type(8))) short bf16x8;
typedef __attribute__((ext_vector_type(4))) float f32x4;

__device__ __forceinline__ unsigned short f2bf(float f) {
    unsigned u = __float_as_uint(f);
    u += 0x7fffu + ((u >> 16) & 1u);   // RNE
    return (unsigned short)(u >> 16);
}

// ================= K1: {gemm1 MFMA (bid%3==0)} interleaved with {csr build} =================
// gemm1: Wh[n][h][o] = x[n][f] @ W[h][f][o] via bf16 MFMA 16x16x32.
// 64x64 tile/block (one head). LDS: W^T staged once [o][f], x staged per 64-K chunk.
// Fused epilogue: f1[n][h] = Wh row · a1[h], f2 likewise (fp32 accs).
__global__ __launch_bounds__(256) void k1_gemm_csr(const float* __restrict__ x,
                                                   const float* __restrict__ W,
                                                   const float* __restrict__ a1,
                                                   const float* __restrict__ a2,
                                                   float* __restrict__ Wh,
                                                   float* __restrict__ f1,
                                                   float* __restrict__ f2,
                                                   const float* __restrict__ adj,
                                                   int* __restrict__ degs,
                                                   int* __restrict__ cols) {
    __shared__ __attribute__((aligned(16))) unsigned short axs[64][72];    // x chunk [row][k]
    __shared__ __attribute__((aligned(16))) unsigned short bws[64][264];   // W^T [o][f]
    int bid = blockIdx.x;
    int t = threadIdx.x;
    if (bid % 3 == 0) {
        // ---------------- GEMM1 (MFMA) ----------------
        int g = bid / 3;
        int h = g & 7;
        int n0 = (g >> 3) * 64;
        int w = t >> 6, l = t & 63;
        // stage W^T (once): coalesced float4 rows of W[k][n] -> scattered b16 writes
        const float4* w4 = (const float4*)(W + (size_t)h * IN_DIM * HID);
        #pragma unroll
        for (int i = 0; i < 16; ++i) {
            int e = t + i * 256;
            int k = e >> 4, c4 = e & 15;
            float4 v = w4[k * 16 + c4];
            bws[4 * c4 + 0][k] = f2bf(v.x);
            bws[4 * c4 + 1][k] = f2bf(v.y);
            bws[4 * c4 + 2][k] = f2bf(v.z);
            bws[4 * c4 + 3][k] = f2bf(v.w);
        }
        int m0 = (w >> 1) * 32;      // row quadrant
        int np = (w & 1) * 32;       // col quadrant
        f32x4 zf = {0.f, 0.f, 0.f, 0.f};
        f32x4 acc[2][2] = {{zf, zf}, {zf, zf}};
        const float4* x4 = (const float4*)x;
        for (int kc = 0; kc < IN_DIM; kc += 64) {
            __syncthreads();
            #pragma unroll
            for (int i = 0; i < 4; ++i) {
                int e = t + i * 256;
                int r = e >> 4, c4 = e & 15;
                float4 v = x4[(size_t)(n0 + r) * (IN_DIM / 4) + (kc >> 2) + c4];
                ushort4 u;
                u.x = f2bf(v.x); u.y = f2bf(v.y); u.z = f2bf(v.z); u.w = f2bf(v.w);
                *(ushort4*)&axs[r][c4 * 4] = u;
            }
            __syncthreads();
            #pragma unroll
            for (int k0 = 0; k0 < 64; k0 += 32) {
                bf16x8 af[2], bfr[2];
                #pragma unroll
                for (int m = 0; m < 2; ++m)
                    af[m] = *(const bf16x8*)&axs[m0 + m * 16 + (l & 15)][k0 + (l >> 4) * 8];
                #pragma unroll
                for (int n = 0; n < 2; ++n)
                    bfr[n] = *(const bf16x8*)&bws[np + n * 16 + (l & 15)][kc + k0 + (l >> 4) * 8];
                #pragma unroll
                for (int m = 0; m < 2; ++m)
                    #pragma unroll
                    for (int n = 0; n < 2; ++n)
                        acc[m][n] = __builtin_amdgcn_mfma_f32_16x16x32_bf16(af[m], bfr[n], acc[m][n], 0, 0, 0);
            }
        }
        __syncthreads();   // done reading axs; reuse as reduction buffer
        float a1c[2], a2c[2];
        #pragma unroll
        for (int n = 0; n < 2; ++n) {
            a1c[n] = a1[h * HID + np + n * 16 + (l & 15)];
            a2c[n] = a2[h * HID + np + n * 16 + (l & 15)];
        }
        float* fred = (float*)&axs[0][0];   // [2(f)][2(wn)][64(row)]
        int wn = w & 1;
        #pragma unroll
        for (int m = 0; m < 2; ++m) {
            #pragma unroll
            for (int r = 0; r < 4; ++r) {
                int row = m0 + m * 16 + (l >> 4) * 4 + r;
                #pragma unroll
                for (int n = 0; n < 2; ++n)
                    Wh[((size_t)(n0 + row) * HEADS + h) * HID + np + n * 16 + (l & 15)] = acc[m][n][r];
                float s1 = acc[m][0][r] * a1c[0] + acc[m][1][r] * a1c[1];
                float s2 = acc[m][0][r] * a2c[0] + acc[m][1][r] * a2c[1];
                #pragma unroll
                for (int off = 8; off; off >>= 1) {
                    s1 += __shfl_xor(s1, off);
                    s2 += __shfl_xor(s2, off);
                }
                if ((l & 15) == 0) {
                    fred[0 * 128 + wn * 64 + row] = s1;
                    fred[1 * 128 + wn * 64 + row] = s2;
                }
            }
        }
        __syncthreads();
        if (t < 64) {
            f1[(size_t)(n0 + t) * HEADS + h] = fred[t] + fred[64 + t];
            f2[(size_t)(n0 + t) * HEADS + h] = fred[128 + t] + fred[192 + t];
        }
    } else {
        // ---------------- CSR build (ballot compact) ----------------
        int cidx = (bid / 3) * 2 + (bid % 3) - 1;   // 0..1023
        int wave = t >> 6;
        int lane = t & 63;
        int row = cidx * 4 + wave;
        const float4* arow = (const float4*)(adj + (size_t)row * N_NODES);
        int base = 0;
        for (int c0 = 0; c0 < N_NODES / 4; c0 += 64) {
            float4 v = arow[c0 + lane];
            float comp[4] = {v.x, v.y, v.z, v.w};
            #pragma unroll
            for (int q = 0; q < 4; ++q) {
                bool pred = comp[q] > 0.f;
                unsigned long long mask = __ballot(pred);
                if (pred) {
                    int pos = base + __popcll(mask & ((1ull << lane) - 1ull));
                    if (pos < MAXDEG) cols[row * MAXDEG + pos] = (c0 + lane) * 4 + q;
                }
                base += __popcll(mask);
            }
        }
        if (lane == 0) degs[row] = base < MAXDEG ? base : MAXDEG;
    }
}

// ================= K2: attention layer 1, one block per node, all 8 heads =================
// Wh fp32 [n][h][o]; out hbufb bf16 [n][512]. PV gather: 512B/wave head-pair float2 loads.
__global__ __launch_bounds__(256) void attn1_node(const float* __restrict__ Wh,
                                                  const float* __restrict__ f1,
                                                  const float* __restrict__ f2,
                                                  const int* __restrict__ degs,
                                                  const int* __restrict__ cols,
                                                  unsigned short* __restrict__ hbufb) {
    __shared__ int cols_s[MAXDEG];
    __shared__ float p_s[HEADS][MAXDEG];
    __shared__ float inv_s[HEADS];
    int n = blockIdx.x;
    int t = threadIdx.x;
    int w = t >> 6, l = t & 63;
    int deg = degs[n];
    if (t < deg) cols_s[t] = cols[n * MAXDEG + t];
    __syncthreads();
    #pragma unroll
    for (int pass = 0; pass < 2; ++pass) {
        int h = 2 * w + pass;
        float e = -1e30f;
        if (l < deg) {
            int cj = cols_s[l];
            float v = f1[n * HEADS + h] + f2[cj * HEADS + h];
            e = v > 0.f ? v : ALPHA * v;
        }
        float m = e;
        #pragma unroll
        for (int off = 32; off; off >>= 1) m = fmaxf(m, __shfl_xor(m, off));
        float p = (l < deg) ? expf(e - m) : 0.f;
        float s = p;
        #pragma unroll
        for (int off = 32; off; off >>= 1) s += __shfl_xor(s, off);
        p_s[h][l] = p;
        if (l == 0) inv_s[h] = 1.f / s;
    }
    __syncthreads();
    int h = 2 * w + (l >> 5);
    float2 acc = make_float2(0.f, 0.f);
    const float2* whp = (const float2*)Wh;
    for (int j = 0; j < deg; ++j) {
        float2 v = whp[(size_t)cols_s[j] * 256 + w * 64 + l];
        float pj = p_s[h][j];
        acc.x += pj * v.x;
        acc.y += pj * v.y;
    }
    float inv = inv_s[h];
    ushort2 o2;
    o2.x = f2bf(acc.x * inv);
    o2.y = f2bf(acc.y * inv);
    *(ushort2*)&hbufb[(size_t)n * 512 + w * 128 + l * 2] = o2;
}

// ================= K3: gemm2 (MFMA) + fused f1/f2 =================
// Wh2[n][o] = hbufb[n][k] @ Wo[k][o], K=512, bf16 MFMA. 64 blocks of 64 rows.
__global__ __launch_bounds__(256) void gemm2_f(const unsigned short* __restrict__ hbufb,
                                               const float* __restrict__ Wo,
                                               const float* __restrict__ a1,
                                               const float* __restrict__ a2,
                                               float* __restrict__ Wh2,
                                               float* __restrict__ f1,
                                               float* __restrict__ f2) {
    __shared__ __attribute__((aligned(16))) unsigned short axs[64][136];
    __shared__ __attribute__((aligned(16))) unsigned short bws[64][136];
    int m0 = blockIdx.x * 64;
    int t = threadIdx.x;
    int w = t >> 6, l = t & 63;
    f32x4 zf = {0.f, 0.f, 0.f, 0.f};
    f32x4 acc[4] = {zf, zf, zf, zf};
    const float4* wo4 = (const float4*)Wo;
    for (int kc = 0; kc < HEADS * HID; kc += 128) {
        __syncthreads();
        #pragma unroll
        for (int i = 0; i < 4; ++i) {      // A: bf16 direct, 16B loads
            int e = t + i * 256;
            int r = e >> 4, c8 = e & 15;
            *(uint4*)&axs[r][c8 * 8] = *(const uint4*)&hbufb[(size_t)(m0 + r) * 512 + kc + c8 * 8];
        }
        #pragma unroll
        for (int i = 0; i < 8; ++i) {      // B^T: coalesced float4 + b16 scatter
            int e = t + i * 256;
            int kk = e >> 4, c4 = e & 15;
            float4 v = wo4[(size_t)(kc + kk) * (OUT_DIM / 4) + c4];
            bws[4 * c4 + 0][kk] = f2bf(v.x);
            bws[4 * c4 + 1][kk] = f2bf(v.y);
            bws[4 * c4 + 2][kk] = f2bf(v.z);
            bws[4 * c4 + 3][kk] = f2bf(v.w);
        }
        __syncthreads();
        #pragma unroll
        for (int k0 = 0; k0 < 128; k0 += 32) {
            bf16x8 af = *(const bf16x8*)&axs[w * 16 + (l & 15)][k0 + (l >> 4) * 8];
            #pragma unroll
            for (int n = 0; n < 4; ++n) {
                bf16x8 bfr = *(const bf16x8*)&bws[n * 16 + (l & 15)][k0 + (l >> 4) * 8];
                acc[n] = __builtin_amdgcn_mfma_f32_16x16x32_bf16(af, bfr, acc[n], 0, 0, 0);
            }
        }
    }
    float a1c[4], a2c[4];
    #pragma unroll
    for (int n = 0; n < 4; ++n) {
        a1c[n] = a1[n * 16 + (l & 15)];
        a2c[n] = a2[n * 16 + (l & 15)];
    }
    #pragma unroll
    for (int r = 0; r < 4; ++r) {
        int row = m0 + w * 16 + (l >> 4) * 4 + r;
        float s1 = 0.f, s2 = 0.f;
        #pragma unroll
        for (int n = 0; n < 4; ++n) {
            Wh2[(size_t)row * OUT_DIM + n * 16 + (l & 15)] = acc[n][r];
            s1 += acc[n][r] * a1c[n];
            s2 += acc[n][r] * a2c[n];
        }
        #pragma unroll
        for (int off = 8; off; off >>= 1) {
            s1 += __shfl_xor(s1, off);
            s2 += __shfl_xor(s2, off);
        }
        if ((l & 15) == 0) {
            f1[row] = s1;
            f2[row] = s2;
        }
    }
}

// ================= K4: attention layer 2 (+ELU), 1 wave per node =================
__global__ __launch_bounds__(256) void attn2(const float* __restrict__ Wh,
                                             const float* __restrict__ f1,
                                             const float* __restrict__ f2,
                                             const int* __restrict__ degs,
                                             const int* __restrict__ cols,
                                             float* __restrict__ out) {
    int wave = threadIdx.x >> 6;
    int lane = threadIdx.x & 63;
    int n = blockIdx.x * 4 + wave;
    if (n >= N_NODES) return;
    int deg = degs[n];
    int col = 0;
    float e = -1e30f;
    if (lane < deg) {
        col = cols[n * MAXDEG + lane];
        float v = f1[n] + f2[col];
        e = v > 0.f ? v : ALPHA * v;
    }
    float m = e;
    #pragma unroll
    for (int off = 32; off; off >>= 1) m = fmaxf(m, __shfl_xor(m, off));
    float p = (lane < deg) ? expf(e - m) : 0.f;
    float s = p;
    #pragma unroll
    for (int off = 32; off; off >>= 1) s += __shfl_xor(s, off);
    float inv = 1.f / s;
    float acc = 0.f;
    for (int j = 0; j < deg; ++j) {
        int cj = __shfl(col, j);
        float pj = __shfl(p, j);
        acc += pj * Wh[(size_t)cj * OUT_DIM + lane];
    }
    acc *= inv;
    acc = acc > 0.f ? acc : expf(acc) - 1.f;   // ELU
    out[(size_t)n * OUT_DIM + lane] = acc;
}

extern "C" void kernel_launch(void* const* d_in, const int* in_sizes, int n_in,
                              void* d_out, int out_size, void* d_ws, size_t ws_size,
                              hipStream_t stream) {
    const float* x    = (const float*)d_in[0];
    const float* adj  = (const float*)d_in[1];
    const float* W_h  = (const float*)d_in[2];
    const float* a1_h = (const float*)d_in[3];
    const float* a2_h = (const float*)d_in[4];
    const float* W_o  = (const float*)d_in[5];
    const float* a1_o = (const float*)d_in[6];
    const float* a2_o = (const float*)d_in[7];
    float* out = (float*)d_out;

    float* wsf  = (float*)d_ws;
    float* Wh1  = wsf;                                  // [n][h][o] fp32, 4096*512
    float* Wh2  = Wh1 + (size_t)N_NODES * HEADS * HID;  // [n][64] fp32
    float* f1_1 = Wh2 + (size_t)N_NODES * OUT_DIM;      // [n][8]
    float* f2_1 = f1_1 + (size_t)N_NODES * HEADS;
    float* f1_2 = f2_1 + (size_t)N_NODES * HEADS;       // [n]
    float* f2_2 = f1_2 + N_NODES;
    int*   degs = (int*)(f2_2 + N_NODES);
    int*   csr  = degs + N_NODES;                       // [n][64]
    unsigned short* hbufb = (unsigned short*)(csr + (size_t)N_NODES * MAXDEG);  // bf16 [n][512]

    // K1: gemm1-MFMA (512 blocks) interleaved with csr build (1024 blocks)
    k1_gemm_csr<<<1536, 256, 0, stream>>>(x, W_h, a1_h, a2_h, Wh1, f1_1, f2_1, adj, degs, csr);

    // K2: attention layer 1 -> hbufb bf16 [n][512]
    attn1_node<<<N_NODES, 256, 0, stream>>>(Wh1, f1_1, f2_1, degs, csr, hbufb);

    // K3: layer-2 GEMM (MFMA) + fused f1/f2
    gemm2_f<<<N_NODES / 64, 256, 0, stream>>>(hbufb, W_o, a1_o, a2_o, Wh2, f1_2, f2_2);

    // K4: attention layer 2 + ELU -> d_out [n][64]
    attn2<<<N_NODES / 4, 256, 0, stream>>>(Wh2, f1_2, f2_2, degs, csr, out);
}

// Round 5
// 65.582 us; speedup vs baseline: 2.8377x; 1.0385x over previous
//
#include <hip/hip_runtime.h>
#include <cstdint>
#include <cstddef>

#define N_NODES 4096
#define IN_DIM 256
#define HID 64
#define HEADS 8
#define OUT_DIM 64
#define ALPHA 0.2f
#define MAXDEG 64

typedef __attribute__((ext_vector_type(8))) short bf16x8;
typedef __attribute__((ext_vector_type(4))) float f32x4;

__device__ __forceinline__ unsigned short f2bf(float f) {
    unsigned u = __float_as_uint(f);
    u += 0x7fffu + ((u >> 16) & 1u);   // RNE
    return (unsigned short)(u >> 16);
}
__device__ __forceinline__ float bf2f(unsigned short u) {
    return __uint_as_float(((unsigned)u) << 16);
}

// ================= K1: {gemm1 MFMA (bid%3==0)} interleaved with {csr build} =================
// gemm1: Whb[n][h][o](bf16) = x[n][f] @ W[h][f][o] via bf16 MFMA 16x16x32.
// 64x64 tile/block (one head). LDS: per-64-K chunk staging of x and W^T (18.4KB -> 8 blk/CU).
// Fused epilogue: f1[n][h], f2[n][h] fp32.
// csr: ballot-compact 4 rows/block of dense adj, software-prefetched.
__global__ __launch_bounds__(256) void k1_gemm_csr(const float* __restrict__ x,
                                                   const float* __restrict__ W,
                                                   const float* __restrict__ a1,
                                                   const float* __restrict__ a2,
                                                   unsigned short* __restrict__ Whb,
                                                   float* __restrict__ f1,
                                                   float* __restrict__ f2,
                                                   const float* __restrict__ adj,
                                                   int* __restrict__ degs,
                                                   int* __restrict__ cols) {
    __shared__ __attribute__((aligned(16))) unsigned short axs[64][72];    // x chunk [row][k]
    __shared__ __attribute__((aligned(16))) unsigned short bws[64][72];    // W^T chunk [o][k]
    int bid = blockIdx.x;
    int t = threadIdx.x;
    if (bid % 3 == 0) {
        // ---------------- GEMM1 (MFMA) ----------------
        int g = bid / 3;
        int h = g & 7;
        int n0 = (g >> 3) * 64;
        int w = t >> 6, l = t & 63;
        int m0 = (w >> 1) * 32;      // row quadrant
        int np = (w & 1) * 32;       // col quadrant
        f32x4 zf = {0.f, 0.f, 0.f, 0.f};
        f32x4 acc[2][2] = {{zf, zf}, {zf, zf}};
        const float4* x4 = (const float4*)x;
        const float4* w4 = (const float4*)(W + (size_t)h * IN_DIM * HID);
        for (int kc = 0; kc < IN_DIM; kc += 64) {
            __syncthreads();
            #pragma unroll
            for (int i = 0; i < 4; ++i) {       // x chunk: 64 rows x 64 k
                int e = t + i * 256;
                int r = e >> 4, c4 = e & 15;
                float4 v = x4[(size_t)(n0 + r) * (IN_DIM / 4) + (kc >> 2) + c4];
                ushort4 u;
                u.x = f2bf(v.x); u.y = f2bf(v.y); u.z = f2bf(v.z); u.w = f2bf(v.w);
                *(ushort4*)&axs[r][c4 * 4] = u;
            }
            #pragma unroll
            for (int i = 0; i < 4; ++i) {       // W^T chunk: rows kc..kc+63 -> [o][kk]
                int e = t + i * 256;
                int kk = e >> 4, c4 = e & 15;
                float4 v = w4[(size_t)(kc + kk) * (HID / 4) + c4];
                bws[4 * c4 + 0][kk] = f2bf(v.x);
                bws[4 * c4 + 1][kk] = f2bf(v.y);
                bws[4 * c4 + 2][kk] = f2bf(v.z);
                bws[4 * c4 + 3][kk] = f2bf(v.w);
            }
            __syncthreads();
            #pragma unroll
            for (int k0 = 0; k0 < 64; k0 += 32) {
                bf16x8 af[2], bfr[2];
                #pragma unroll
                for (int m = 0; m < 2; ++m)
                    af[m] = *(const bf16x8*)&axs[m0 + m * 16 + (l & 15)][k0 + (l >> 4) * 8];
                #pragma unroll
                for (int n = 0; n < 2; ++n)
                    bfr[n] = *(const bf16x8*)&bws[np + n * 16 + (l & 15)][k0 + (l >> 4) * 8];
                #pragma unroll
                for (int m = 0; m < 2; ++m)
                    #pragma unroll
                    for (int n = 0; n < 2; ++n)
                        acc[m][n] = __builtin_amdgcn_mfma_f32_16x16x32_bf16(af[m], bfr[n], acc[m][n], 0, 0, 0);
            }
        }
        __syncthreads();   // done with LDS; reuse axs as reduction buffer
        float a1c[2], a2c[2];
        #pragma unroll
        for (int n = 0; n < 2; ++n) {
            a1c[n] = a1[h * HID + np + n * 16 + (l & 15)];
            a2c[n] = a2[h * HID + np + n * 16 + (l & 15)];
        }
        float* fred = (float*)&axs[0][0];   // [2(f)][2(wn)][64(row)]
        int wn = w & 1;
        #pragma unroll
        for (int m = 0; m < 2; ++m) {
            #pragma unroll
            for (int r = 0; r < 4; ++r) {
                int row = m0 + m * 16 + (l >> 4) * 4 + r;
                #pragma unroll
                for (int n = 0; n < 2; ++n)
                    Whb[((size_t)(n0 + row) * HEADS + h) * HID + np + n * 16 + (l & 15)] =
                        f2bf(acc[m][n][r]);
                float s1 = acc[m][0][r] * a1c[0] + acc[m][1][r] * a1c[1];
                float s2 = acc[m][0][r] * a2c[0] + acc[m][1][r] * a2c[1];
                #pragma unroll
                for (int off = 8; off; off >>= 1) {
                    s1 += __shfl_xor(s1, off);
                    s2 += __shfl_xor(s2, off);
                }
                if ((l & 15) == 0) {
                    fred[0 * 128 + wn * 64 + row] = s1;
                    fred[1 * 128 + wn * 64 + row] = s2;
                }
            }
        }
        __syncthreads();
        if (t < 64) {
            f1[(size_t)(n0 + t) * HEADS + h] = fred[t] + fred[64 + t];
            f2[(size_t)(n0 + t) * HEADS + h] = fred[128 + t] + fred[192 + t];
        }
    } else {
        // ---------------- CSR build (ballot compact, prefetched) ----------------
        int cidx = (bid / 3) * 2 + (bid % 3) - 1;   // 0..1023
        int wave = t >> 6;
        int lane = t & 63;
        int row = cidx * 4 + wave;
        const float4* arow = (const float4*)(adj + (size_t)row * N_NODES);
        float4 v = arow[lane];
        int base = 0;
        for (int c0 = 0; c0 < N_NODES / 4; c0 += 64) {
            float4 vn;
            if (c0 + 64 < N_NODES / 4) vn = arow[c0 + 64 + lane];   // prefetch next chunk
            float comp[4] = {v.x, v.y, v.z, v.w};
            #pragma unroll
            for (int q = 0; q < 4; ++q) {
                bool pred = comp[q] > 0.f;
                unsigned long long mask = __ballot(pred);
                if (pred) {
                    int pos = base + __popcll(mask & ((1ull << lane) - 1ull));
                    if (pos < MAXDEG) cols[row * MAXDEG + pos] = (c0 + lane) * 4 + q;
                }
                base += __popcll(mask);
            }
            v = vn;
        }
        if (lane == 0) degs[row] = base < MAXDEG ? base : MAXDEG;
    }
}

// ================= K2: attention layer 1, one block per node, all 8 heads =================
// Whb bf16 [n][h][o]; out hbufb bf16 [n][512]. PV gather: 256B/wave ushort2 loads.
__global__ __launch_bounds__(256) void attn1_node(const unsigned short* __restrict__ Whb,
                                                  const float* __restrict__ f1,
                                                  const float* __restrict__ f2,
                                                  const int* __restrict__ degs,
                                                  const int* __restrict__ cols,
                                                  unsigned short* __restrict__ hbufb) {
    __shared__ int cols_s[MAXDEG];
    __shared__ float p_s[HEADS][MAXDEG];
    __shared__ float inv_s[HEADS];
    int n = blockIdx.x;
    int t = threadIdx.x;
    int w = t >> 6, l = t & 63;
    int deg = degs[n];
    if (t < deg) cols_s[t] = cols[n * MAXDEG + t];
    __syncthreads();
    #pragma unroll
    for (int pass = 0; pass < 2; ++pass) {
        int h = 2 * w + pass;
        float e = -1e30f;
        if (l < deg) {
            int cj = cols_s[l];
            float v = f1[n * HEADS + h] + f2[cj * HEADS + h];
            e = v > 0.f ? v : ALPHA * v;
        }
        float m = e;
        #pragma unroll
        for (int off = 32; off; off >>= 1) m = fmaxf(m, __shfl_xor(m, off));
        float p = (l < deg) ? expf(e - m) : 0.f;
        float s = p;
        #pragma unroll
        for (int off = 32; off; off >>= 1) s += __shfl_xor(s, off);
        p_s[h][l] = p;
        if (l == 0) inv_s[h] = 1.f / s;
    }
    __syncthreads();
    int h = 2 * w + (l >> 5);
    float2 acc = make_float2(0.f, 0.f);
    const ushort2* whp = (const ushort2*)Whb;   // [n][256] ushort2
    for (int j = 0; j < deg; ++j) {
        ushort2 u = whp[(size_t)cols_s[j] * 256 + w * 64 + l];
        float pj = p_s[h][j];
        acc.x += pj * bf2f(u.x);
        acc.y += pj * bf2f(u.y);
    }
    float inv = inv_s[h];
    ushort2 o2;
    o2.x = f2bf(acc.x * inv);
    o2.y = f2bf(acc.y * inv);
    *(ushort2*)&hbufb[(size_t)n * 512 + w * 128 + l * 2] = o2;
}

// ================= K3: gemm2 (MFMA) + fused f1/f2 =================
// Wh2[n][o] = hbufb[n][k] @ Wo[k][o], K=512, bf16 MFMA. 64 blocks of 64 rows.
__global__ __launch_bounds__(256) void gemm2_f(const unsigned short* __restrict__ hbufb,
                                               const float* __restrict__ Wo,
                                               const float* __restrict__ a1,
                                               const float* __restrict__ a2,
                                               float* __restrict__ Wh2,
                                               float* __restrict__ f1,
                                               float* __restrict__ f2) {
    __shared__ __attribute__((aligned(16))) unsigned short axs[64][136];
    __shared__ __attribute__((aligned(16))) unsigned short bws[64][136];
    int m0 = blockIdx.x * 64;
    int t = threadIdx.x;
    int w = t >> 6, l = t & 63;
    f32x4 zf = {0.f, 0.f, 0.f, 0.f};
    f32x4 acc[4] = {zf, zf, zf, zf};
    const float4* wo4 = (const float4*)Wo;
    for (int kc = 0; kc < HEADS * HID; kc += 128) {
        __syncthreads();
        #pragma unroll
        for (int i = 0; i < 4; ++i) {      // A: bf16 direct, 16B loads
            int e = t + i * 256;
            int r = e >> 4, c8 = e & 15;
            *(uint4*)&axs[r][c8 * 8] = *(const uint4*)&hbufb[(size_t)(m0 + r) * 512 + kc + c8 * 8];
        }
        #pragma unroll
        for (int i = 0; i < 8; ++i) {      // B^T: coalesced float4 + b16 scatter
            int e = t + i * 256;
            int kk = e >> 4, c4 = e & 15;
            float4 v = wo4[(size_t)(kc + kk) * (OUT_DIM / 4) + c4];
            bws[4 * c4 + 0][kk] = f2bf(v.x);
            bws[4 * c4 + 1][kk] = f2bf(v.y);
            bws[4 * c4 + 2][kk] = f2bf(v.z);
            bws[4 * c4 + 3][kk] = f2bf(v.w);
        }
        __syncthreads();
        #pragma unroll
        for (int k0 = 0; k0 < 128; k0 += 32) {
            bf16x8 af = *(const bf16x8*)&axs[w * 16 + (l & 15)][k0 + (l >> 4) * 8];
            #pragma unroll
            for (int n = 0; n < 4; ++n) {
                bf16x8 bfr = *(const bf16x8*)&bws[n * 16 + (l & 15)][k0 + (l >> 4) * 8];
                acc[n] = __builtin_amdgcn_mfma_f32_16x16x32_bf16(af, bfr, acc[n], 0, 0, 0);
            }
        }
    }
    float a1c[4], a2c[4];
    #pragma unroll
    for (int n = 0; n < 4; ++n) {
        a1c[n] = a1[n * 16 + (l & 15)];
        a2c[n] = a2[n * 16 + (l & 15)];
    }
    #pragma unroll
    for (int r = 0; r < 4; ++r) {
        int row = m0 + w * 16 + (l >> 4) * 4 + r;
        float s1 = 0.f, s2 = 0.f;
        #pragma unroll
        for (int n = 0; n < 4; ++n) {
            Wh2[(size_t)row * OUT_DIM + n * 16 + (l & 15)] = acc[n][r];
            s1 += acc[n][r] * a1c[n];
            s2 += acc[n][r] * a2c[n];
        }
        #pragma unroll
        for (int off = 8; off; off >>= 1) {
            s1 += __shfl_xor(s1, off);
            s2 += __shfl_xor(s2, off);
        }
        if ((l & 15) == 0) {
            f1[row] = s1;
            f2[row] = s2;
        }
    }
}

// ================= K4: attention layer 2 (+ELU), 1 wave per node =================
__global__ __launch_bounds__(256) void attn2(const float* __restrict__ Wh,
                                             const float* __restrict__ f1,
                                             const float* __restrict__ f2,
                                             const int* __restrict__ degs,
                                             const int* __restrict__ cols,
                                             float* __restrict__ out) {
    int wave = threadIdx.x >> 6;
    int lane = threadIdx.x & 63;
    int n = blockIdx.x * 4 + wave;
    if (n >= N_NODES) return;
    int deg = degs[n];
    int col = 0;
    float e = -1e30f;
    if (lane < deg) {
        col = cols[n * MAXDEG + lane];
        float v = f1[n] + f2[col];
        e = v > 0.f ? v : ALPHA * v;
    }
    float m = e;
    #pragma unroll
    for (int off = 32; off; off >>= 1) m = fmaxf(m, __shfl_xor(m, off));
    float p = (lane < deg) ? expf(e - m) : 0.f;
    float s = p;
    #pragma unroll
    for (int off = 32; off; off >>= 1) s += __shfl_xor(s, off);
    float inv = 1.f / s;
    float acc = 0.f;
    for (int j = 0; j < deg; ++j) {
        int cj = __shfl(col, j);
        float pj = __shfl(p, j);
        acc += pj * Wh[(size_t)cj * OUT_DIM + lane];
    }
    acc *= inv;
    acc = acc > 0.f ? acc : expf(acc) - 1.f;   // ELU
    out[(size_t)n * OUT_DIM + lane] = acc;
}

extern "C" void kernel_launch(void* const* d_in, const int* in_sizes, int n_in,
                              void* d_out, int out_size, void* d_ws, size_t ws_size,
                              hipStream_t stream) {
    const float* x    = (const float*)d_in[0];
    const float* adj  = (const float*)d_in[1];
    const float* W_h  = (const float*)d_in[2];
    const float* a1_h = (const float*)d_in[3];
    const float* a2_h = (const float*)d_in[4];
    const float* W_o  = (const float*)d_in[5];
    const float* a1_o = (const float*)d_in[6];
    const float* a2_o = (const float*)d_in[7];
    float* out = (float*)d_out;

    float* wsf  = (float*)d_ws;
    float* Wh2  = wsf;                                  // [n][64] fp32
    float* f1_1 = Wh2 + (size_t)N_NODES * OUT_DIM;      // [n][8]
    float* f2_1 = f1_1 + (size_t)N_NODES * HEADS;
    float* f1_2 = f2_1 + (size_t)N_NODES * HEADS;       // [n]
    float* f2_2 = f1_2 + N_NODES;
    int*   degs = (int*)(f2_2 + N_NODES);
    int*   csr  = degs + N_NODES;                       // [n][64]
    unsigned short* Whb   = (unsigned short*)(csr + (size_t)N_NODES * MAXDEG); // bf16 [n][h][o]
    unsigned short* hbufb = Whb + (size_t)N_NODES * HEADS * HID;               // bf16 [n][512]

    // K1: gemm1-MFMA (512 blocks) interleaved with csr build (1024 blocks)
    k1_gemm_csr<<<1536, 256, 0, stream>>>(x, W_h, a1_h, a2_h, Whb, f1_1, f2_1, adj, degs, csr);

    // K2: attention layer 1 -> hbufb bf16 [n][512]
    attn1_node<<<N_NODES, 256, 0, stream>>>(Whb, f1_1, f2_1, degs, csr, hbufb);

    // K3: layer-2 GEMM (MFMA) + fused f1/f2
    gemm2_f<<<N_NODES / 64, 256, 0, stream>>>(hbufb, W_o, a1_o, a2_o, Wh2, f1_2, f2_2);

    // K4: attention layer 2 + ELU -> d_out [n][64]
    attn2<<<N_NODES / 4, 256, 0, stream>>>(Wh2, f1_2, f2_2, degs, csr, out);
}

// Round 6
// 64.717 us; speedup vs baseline: 2.8756x; 1.0134x over previous
//
#include <hip/hip_runtime.h>
#include <cstdint>
#include <cstddef>

#define N_NODES 4096
#define IN_DIM 256
#define HID 64
#define HEADS 8
#define OUT_DIM 64
#define ALPHA 0.2f
#define MAXDEG 64

typedef __attribute__((ext_vector_type(8))) short bf16x8;
typedef __attribute__((ext_vector_type(4))) float f32x4;

__device__ __forceinline__ unsigned short f2bf(float f) {
    unsigned u = __float_as_uint(f);
    u += 0x7fffu + ((u >> 16) & 1u);   // RNE
    return (unsigned short)(u >> 16);
}
__device__ __forceinline__ float bf2f(unsigned short u) {
    return __uint_as_float(((unsigned)u) << 16);
}

// ================= K1: {gemm1 MFMA (bid%9==0)} interleaved with {csr: 1 block per row} =======
// gemm1: Whb[n][h][o](bf16) = x[n][f] @ W[h][f][o] via bf16 MFMA 16x16x32. 64x64 tile/block.
// csr: block = one adj row; wave w scans cols [w*1024,(w+1)*1024) with 4 indep float4 loads
//      up front (16KB/block in flight), ballot-compacts to LDS, 4-wave prefix, write-out.
__global__ __launch_bounds__(256) void k1_gemm_csr(const float* __restrict__ x,
                                                   const float* __restrict__ W,
                                                   const float* __restrict__ a1,
                                                   const float* __restrict__ a2,
                                                   unsigned short* __restrict__ Whb,
                                                   float* __restrict__ f1,
                                                   float* __restrict__ f2,
                                                   const float* __restrict__ adj,
                                                   int* __restrict__ degs,
                                                   int* __restrict__ cols) {
    __shared__ __attribute__((aligned(16))) unsigned short axs[64][72];    // x chunk [row][k]
    __shared__ __attribute__((aligned(16))) unsigned short bws[64][72];    // W^T chunk [o][k]
    int bid = blockIdx.x;
    int t = threadIdx.x;
    int w = t >> 6, l = t & 63;
    if (bid % 9 == 0) {
        // ---------------- GEMM1 (MFMA) ----------------
        int g = bid / 9;
        int h = g & 7;
        int n0 = (g >> 3) * 64;
        int m0 = (w >> 1) * 32;      // row quadrant
        int np = (w & 1) * 32;       // col quadrant
        f32x4 zf = {0.f, 0.f, 0.f, 0.f};
        f32x4 acc[2][2] = {{zf, zf}, {zf, zf}};
        const float4* x4 = (const float4*)x;
        const float4* w4 = (const float4*)(W + (size_t)h * IN_DIM * HID);
        for (int kc = 0; kc < IN_DIM; kc += 64) {
            __syncthreads();
            #pragma unroll
            for (int i = 0; i < 4; ++i) {       // x chunk: 64 rows x 64 k
                int e = t + i * 256;
                int r = e >> 4, c4 = e & 15;
                float4 v = x4[(size_t)(n0 + r) * (IN_DIM / 4) + (kc >> 2) + c4];
                ushort4 u;
                u.x = f2bf(v.x); u.y = f2bf(v.y); u.z = f2bf(v.z); u.w = f2bf(v.w);
                *(ushort4*)&axs[r][c4 * 4] = u;
            }
            #pragma unroll
            for (int i = 0; i < 4; ++i) {       // W^T chunk: rows kc..kc+63 -> [o][kk]
                int e = t + i * 256;
                int kk = e >> 4, c4 = e & 15;
                float4 v = w4[(size_t)(kc + kk) * (HID / 4) + c4];
                bws[4 * c4 + 0][kk] = f2bf(v.x);
                bws[4 * c4 + 1][kk] = f2bf(v.y);
                bws[4 * c4 + 2][kk] = f2bf(v.z);
                bws[4 * c4 + 3][kk] = f2bf(v.w);
            }
            __syncthreads();
            #pragma unroll
            for (int k0 = 0; k0 < 64; k0 += 32) {
                bf16x8 af[2], bfr[2];
                #pragma unroll
                for (int m = 0; m < 2; ++m)
                    af[m] = *(const bf16x8*)&axs[m0 + m * 16 + (l & 15)][k0 + (l >> 4) * 8];
                #pragma unroll
                for (int n = 0; n < 2; ++n)
                    bfr[n] = *(const bf16x8*)&bws[np + n * 16 + (l & 15)][k0 + (l >> 4) * 8];
                #pragma unroll
                for (int m = 0; m < 2; ++m)
                    #pragma unroll
                    for (int n = 0; n < 2; ++n)
                        acc[m][n] = __builtin_amdgcn_mfma_f32_16x16x32_bf16(af[m], bfr[n], acc[m][n], 0, 0, 0);
            }
        }
        __syncthreads();   // done with LDS; reuse axs as reduction buffer
        float a1c[2], a2c[2];
        #pragma unroll
        for (int n = 0; n < 2; ++n) {
            a1c[n] = a1[h * HID + np + n * 16 + (l & 15)];
            a2c[n] = a2[h * HID + np + n * 16 + (l & 15)];
        }
        float* fred = (float*)&axs[0][0];   // [2(f)][2(wn)][64(row)]
        int wn = w & 1;
        #pragma unroll
        for (int m = 0; m < 2; ++m) {
            #pragma unroll
            for (int r = 0; r < 4; ++r) {
                int row = m0 + m * 16 + (l >> 4) * 4 + r;
                #pragma unroll
                for (int n = 0; n < 2; ++n)
                    Whb[((size_t)(n0 + row) * HEADS + h) * HID + np + n * 16 + (l & 15)] =
                        f2bf(acc[m][n][r]);
                float s1 = acc[m][0][r] * a1c[0] + acc[m][1][r] * a1c[1];
                float s2 = acc[m][0][r] * a2c[0] + acc[m][1][r] * a2c[1];
                #pragma unroll
                for (int off = 8; off; off >>= 1) {
                    s1 += __shfl_xor(s1, off);
                    s2 += __shfl_xor(s2, off);
                }
                if ((l & 15) == 0) {
                    fred[0 * 128 + wn * 64 + row] = s1;
                    fred[1 * 128 + wn * 64 + row] = s2;
                }
            }
        }
        __syncthreads();
        if (t < 64) {
            f1[(size_t)(n0 + t) * HEADS + h] = fred[t] + fred[64 + t];
            f2[(size_t)(n0 + t) * HEADS + h] = fred[128 + t] + fred[192 + t];
        }
    } else {
        // ---------------- CSR build: one block per adj row ----------------
        int g = bid / 9, r9 = bid % 9;
        int row = g * 8 + r9 - 1;               // 0..4095
        int* wcols = (int*)&axs[0][0];          // [4][MAXDEG] overlay on LDS
        int* wcnt  = (int*)&bws[0][0];          // [4]
        const float4* arow = (const float4*)(adj + (size_t)row * N_NODES);
        // issue all 4 segment loads up front (independent -> 4 outstanding/lane)
        float4 v0 = arow[w * 256 + 0 * 64 + l];
        float4 v1 = arow[w * 256 + 1 * 64 + l];
        float4 v2 = arow[w * 256 + 2 * 64 + l];
        float4 v3 = arow[w * 256 + 3 * 64 + l];
        int base = 0;
        float4 vv[4] = {v0, v1, v2, v3};
        #pragma unroll
        for (int i = 0; i < 4; ++i) {
            float comp[4] = {vv[i].x, vv[i].y, vv[i].z, vv[i].w};
            #pragma unroll
            for (int q = 0; q < 4; ++q) {
                bool pred = comp[q] > 0.f;
                unsigned long long mask = __ballot(pred);
                if (pred) {
                    int pos = base + __popcll(mask & ((1ull << l) - 1ull));
                    if (pos < MAXDEG) wcols[w * MAXDEG + pos] = (w * 256 + i * 64 + l) * 4 + q;
                }
                base += __popcll(mask);
            }
        }
        if (l == 0) wcnt[w] = base < MAXDEG ? base : MAXDEG;
        __syncthreads();
        int c0 = wcnt[0], c1 = wcnt[1], c2 = wcnt[2], c3 = wcnt[3];
        int off = (w > 0 ? c0 : 0) + (w > 1 ? c1 : 0) + (w > 2 ? c2 : 0);
        int mycnt = wcnt[w];
        if (l < mycnt) {
            int gpos = off + l;
            if (gpos < MAXDEG) cols[row * MAXDEG + gpos] = wcols[w * MAXDEG + l];
        }
        if (t == 0) {
            int tot = c0 + c1 + c2 + c3;
            degs[row] = tot < MAXDEG ? tot : MAXDEG;
        }
    }
}

// ================= K2: attention layer 1, one block per node, all 8 heads =================
// Whb bf16 [n][h][o]; out hbufb bf16 [n][512]. PV gather 2-way unrolled for MLP.
__global__ __launch_bounds__(256) void attn1_node(const unsigned short* __restrict__ Whb,
                                                  const float* __restrict__ f1,
                                                  const float* __restrict__ f2,
                                                  const int* __restrict__ degs,
                                                  const int* __restrict__ cols,
                                                  unsigned short* __restrict__ hbufb) {
    __shared__ int cols_s[MAXDEG];
    __shared__ float p_s[HEADS][MAXDEG];
    __shared__ float inv_s[HEADS];
    int n = blockIdx.x;
    int t = threadIdx.x;
    int w = t >> 6, l = t & 63;
    int deg = degs[n];
    if (t < deg) cols_s[t] = cols[n * MAXDEG + t];
    __syncthreads();
    #pragma unroll
    for (int pass = 0; pass < 2; ++pass) {
        int h = 2 * w + pass;
        float e = -1e30f;
        if (l < deg) {
            int cj = cols_s[l];
            float v = f1[n * HEADS + h] + f2[cj * HEADS + h];
            e = v > 0.f ? v : ALPHA * v;
        }
        float m = e;
        #pragma unroll
        for (int off = 32; off; off >>= 1) m = fmaxf(m, __shfl_xor(m, off));
        float p = (l < deg) ? expf(e - m) : 0.f;
        float s = p;
        #pragma unroll
        for (int off = 32; off; off >>= 1) s += __shfl_xor(s, off);
        p_s[h][l] = p;
        if (l == 0) inv_s[h] = 1.f / s;
    }
    __syncthreads();
    int h = 2 * w + (l >> 5);
    float2 a0 = make_float2(0.f, 0.f), a1v = make_float2(0.f, 0.f);
    const ushort2* whp = (const ushort2*)Whb;   // [n][256] ushort2
    int j = 0;
    for (; j + 1 < deg; j += 2) {
        ushort2 u0 = whp[(size_t)cols_s[j] * 256 + w * 64 + l];
        ushort2 u1 = whp[(size_t)cols_s[j + 1] * 256 + w * 64 + l];
        float p0 = p_s[h][j], p1 = p_s[h][j + 1];
        a0.x += p0 * bf2f(u0.x); a0.y += p0 * bf2f(u0.y);
        a1v.x += p1 * bf2f(u1.x); a1v.y += p1 * bf2f(u1.y);
    }
    if (j < deg) {
        ushort2 u0 = whp[(size_t)cols_s[j] * 256 + w * 64 + l];
        float p0 = p_s[h][j];
        a0.x += p0 * bf2f(u0.x); a0.y += p0 * bf2f(u0.y);
    }
    float inv = inv_s[h];
    ushort2 o2;
    o2.x = f2bf((a0.x + a1v.x) * inv);
    o2.y = f2bf((a0.y + a1v.y) * inv);
    *(ushort2*)&hbufb[(size_t)n * 512 + w * 128 + l * 2] = o2;
}

// ================= K3: gemm2 (MFMA) + fused f1/f2 =================
// Wh2[n][o] = hbufb[n][k] @ Wo[k][o], K=512, bf16 MFMA. 64 blocks of 64 rows.
__global__ __launch_bounds__(256) void gemm2_f(const unsigned short* __restrict__ hbufb,
                                               const float* __restrict__ Wo,
                                               const float* __restrict__ a1,
                                               const float* __restrict__ a2,
                                               float* __restrict__ Wh2,
                                               float* __restrict__ f1,
                                               float* __restrict__ f2) {
    __shared__ __attribute__((aligned(16))) unsigned short axs[64][136];
    __shared__ __attribute__((aligned(16))) unsigned short bws[64][136];
    int m0 = blockIdx.x * 64;
    int t = threadIdx.x;
    int w = t >> 6, l = t & 63;
    f32x4 zf = {0.f, 0.f, 0.f, 0.f};
    f32x4 acc[4] = {zf, zf, zf, zf};
    const float4* wo4 = (const float4*)Wo;
    for (int kc = 0; kc < HEADS * HID; kc += 128) {
        __syncthreads();
        #pragma unroll
        for (int i = 0; i < 4; ++i) {      // A: bf16 direct, 16B loads
            int e = t + i * 256;
            int r = e >> 4, c8 = e & 15;
            *(uint4*)&axs[r][c8 * 8] = *(const uint4*)&hbufb[(size_t)(m0 + r) * 512 + kc + c8 * 8];
        }
        #pragma unroll
        for (int i = 0; i < 8; ++i) {      // B^T: coalesced float4 + b16 scatter
            int e = t + i * 256;
            int kk = e >> 4, c4 = e & 15;
            float4 v = wo4[(size_t)(kc + kk) * (OUT_DIM / 4) + c4];
            bws[4 * c4 + 0][kk] = f2bf(v.x);
            bws[4 * c4 + 1][kk] = f2bf(v.y);
            bws[4 * c4 + 2][kk] = f2bf(v.z);
            bws[4 * c4 + 3][kk] = f2bf(v.w);
        }
        __syncthreads();
        #pragma unroll
        for (int k0 = 0; k0 < 128; k0 += 32) {
            bf16x8 af = *(const bf16x8*)&axs[w * 16 + (l & 15)][k0 + (l >> 4) * 8];
            #pragma unroll
            for (int n = 0; n < 4; ++n) {
                bf16x8 bfr = *(const bf16x8*)&bws[n * 16 + (l & 15)][k0 + (l >> 4) * 8];
                acc[n] = __builtin_amdgcn_mfma_f32_16x16x32_bf16(af, bfr, acc[n], 0, 0, 0);
            }
        }
    }
    float a1c[4], a2c[4];
    #pragma unroll
    for (int n = 0; n < 4; ++n) {
        a1c[n] = a1[n * 16 + (l & 15)];
        a2c[n] = a2[n * 16 + (l & 15)];
    }
    #pragma unroll
    for (int r = 0; r < 4; ++r) {
        int row = m0 + w * 16 + (l >> 4) * 4 + r;
        float s1 = 0.f, s2 = 0.f;
        #pragma unroll
        for (int n = 0; n < 4; ++n) {
            Wh2[(size_t)row * OUT_DIM + n * 16 + (l & 15)] = acc[n][r];
            s1 += acc[n][r] * a1c[n];
            s2 += acc[n][r] * a2c[n];
        }
        #pragma unroll
        for (int off = 8; off; off >>= 1) {
            s1 += __shfl_xor(s1, off);
            s2 += __shfl_xor(s2, off);
        }
        if ((l & 15) == 0) {
            f1[row] = s1;
            f2[row] = s2;
        }
    }
}

// ================= K4: attention layer 2 (+ELU), 1 wave per node =================
__global__ __launch_bounds__(256) void attn2(const float* __restrict__ Wh,
                                             const float* __restrict__ f1,
                                             const float* __restrict__ f2,
                                             const int* __restrict__ degs,
                                             const int* __restrict__ cols,
                                             float* __restrict__ out) {
    int wave = threadIdx.x >> 6;
    int lane = threadIdx.x & 63;
    int n = blockIdx.x * 4 + wave;
    if (n >= N_NODES) return;
    int deg = degs[n];
    int col = 0;
    float e = -1e30f;
    if (lane < deg) {
        col = cols[n * MAXDEG + lane];
        float v = f1[n] + f2[col];
        e = v > 0.f ? v : ALPHA * v;
    }
    float m = e;
    #pragma unroll
    for (int off = 32; off; off >>= 1) m = fmaxf(m, __shfl_xor(m, off));
    float p = (lane < deg) ? expf(e - m) : 0.f;
    float s = p;
    #pragma unroll
    for (int off = 32; off; off >>= 1) s += __shfl_xor(s, off);
    float inv = 1.f / s;
    float acc0 = 0.f, acc1 = 0.f;
    int j = 0;
    for (; j + 1 < deg; j += 2) {
        int cj0 = __shfl(col, j);
        int cj1 = __shfl(col, j + 1);
        float pj0 = __shfl(p, j);
        float pj1 = __shfl(p, j + 1);
        acc0 += pj0 * Wh[(size_t)cj0 * OUT_DIM + lane];
        acc1 += pj1 * Wh[(size_t)cj1 * OUT_DIM + lane];
    }
    if (j < deg) {
        int cj0 = __shfl(col, j);
        float pj0 = __shfl(p, j);
        acc0 += pj0 * Wh[(size_t)cj0 * OUT_DIM + lane];
    }
    float acc = (acc0 + acc1) * inv;
    acc = acc > 0.f ? acc : expf(acc) - 1.f;   // ELU
    out[(size_t)n * OUT_DIM + lane] = acc;
}

extern "C" void kernel_launch(void* const* d_in, const int* in_sizes, int n_in,
                              void* d_out, int out_size, void* d_ws, size_t ws_size,
                              hipStream_t stream) {
    const float* x    = (const float*)d_in[0];
    const float* adj  = (const float*)d_in[1];
    const float* W_h  = (const float*)d_in[2];
    const float* a1_h = (const float*)d_in[3];
    const float* a2_h = (const float*)d_in[4];
    const float* W_o  = (const float*)d_in[5];
    const float* a1_o = (const float*)d_in[6];
    const float* a2_o = (const float*)d_in[7];
    float* out = (float*)d_out;

    float* wsf  = (float*)d_ws;
    float* Wh2  = wsf;                                  // [n][64] fp32
    float* f1_1 = Wh2 + (size_t)N_NODES * OUT_DIM;      // [n][8]
    float* f2_1 = f1_1 + (size_t)N_NODES * HEADS;
    float* f1_2 = f2_1 + (size_t)N_NODES * HEADS;       // [n]
    float* f2_2 = f1_2 + N_NODES;
    int*   degs = (int*)(f2_2 + N_NODES);
    int*   csr  = degs + N_NODES;                       // [n][64]
    unsigned short* Whb   = (unsigned short*)(csr + (size_t)N_NODES * MAXDEG); // bf16 [n][h][o]
    unsigned short* hbufb = Whb + (size_t)N_NODES * HEADS * HID;               // bf16 [n][512]

    // K1: gemm1-MFMA (512 blocks, bid%9==0) interleaved with csr build (4096 blocks, 1/row)
    k1_gemm_csr<<<4608, 256, 0, stream>>>(x, W_h, a1_h, a2_h, Whb, f1_1, f2_1, adj, degs, csr);

    // K2: attention layer 1 -> hbufb bf16 [n][512]
    attn1_node<<<N_NODES, 256, 0, stream>>>(Whb, f1_1, f2_1, degs, csr, hbufb);

    // K3: layer-2 GEMM (MFMA) + fused f1/f2
    gemm2_f<<<N_NODES / 64, 256, 0, stream>>>(hbufb, W_o, a1_o, a2_o, Wh2, f1_2, f2_2);

    // K4: attention layer 2 + ELU -> d_out [n][64]
    attn2<<<N_NODES / 4, 256, 0, stream>>>(Wh2, f1_2, f2_2, degs, csr, out);
}

// Round 8
// 58.137 us; speedup vs baseline: 3.2010x; 1.1132x over previous
//
#include <hip/hip_runtime.h>
#include <cstdint>
#include <cstddef>

#define N_NODES 4096
#define IN_DIM 256
#define HID 64
#define HEADS 8
#define OUT_DIM 64
#define ALPHA 0.2f
#define MAXDEG 64

typedef __attribute__((ext_vector_type(8))) short bf16x8;
typedef __attribute__((ext_vector_type(4))) float f32x4;

__device__ __forceinline__ unsigned short f2bf(float f) {
    unsigned u = __float_as_uint(f);
    u += 0x7fffu + ((u >> 16) & 1u);   // RNE
    return (unsigned short)(u >> 16);
}
__device__ __forceinline__ float bf2f(unsigned short u) {
    return __uint_as_float(((unsigned)u) << 16);
}

// ================= K1: {gemm1 MFMA (bid%9==0)} interleaved with {csr: 1 block per row} =======
__global__ __launch_bounds__(256) void k1_gemm_csr(const float* __restrict__ x,
                                                   const float* __restrict__ W,
                                                   const float* __restrict__ a1,
                                                   const float* __restrict__ a2,
                                                   unsigned short* __restrict__ Whb,
                                                   float* __restrict__ f1,
                                                   float* __restrict__ f2,
                                                   const float* __restrict__ adj,
                                                   int* __restrict__ degs,
                                                   int* __restrict__ cols) {
    __shared__ __attribute__((aligned(16))) unsigned short axs[64][72];    // x chunk [row][k]
    __shared__ __attribute__((aligned(16))) unsigned short bws[64][72];    // W^T chunk [o][k]
    int bid = blockIdx.x;
    int t = threadIdx.x;
    int w = t >> 6, l = t & 63;
    if (bid % 9 == 0) {
        // ---------------- GEMM1 (MFMA) ----------------
        int g = bid / 9;
        int h = g & 7;
        int n0 = (g >> 3) * 64;
        int m0 = (w >> 1) * 32;      // row quadrant
        int np = (w & 1) * 32;       // col quadrant
        f32x4 zf = {0.f, 0.f, 0.f, 0.f};
        f32x4 acc[2][2] = {{zf, zf}, {zf, zf}};
        const float4* x4 = (const float4*)x;
        const float4* w4 = (const float4*)(W + (size_t)h * IN_DIM * HID);
        for (int kc = 0; kc < IN_DIM; kc += 64) {
            __syncthreads();
            #pragma unroll
            for (int i = 0; i < 4; ++i) {       // x chunk: 64 rows x 64 k
                int e = t + i * 256;
                int r = e >> 4, c4 = e & 15;
                float4 v = x4[(size_t)(n0 + r) * (IN_DIM / 4) + (kc >> 2) + c4];
                ushort4 u;
                u.x = f2bf(v.x); u.y = f2bf(v.y); u.z = f2bf(v.z); u.w = f2bf(v.w);
                *(ushort4*)&axs[r][c4 * 4] = u;
            }
            #pragma unroll
            for (int i = 0; i < 4; ++i) {       // W^T chunk: rows kc..kc+63 -> [o][kk]
                int e = t + i * 256;
                int kk = e >> 4, c4 = e & 15;
                float4 v = w4[(size_t)(kc + kk) * (HID / 4) + c4];
                bws[4 * c4 + 0][kk] = f2bf(v.x);
                bws[4 * c4 + 1][kk] = f2bf(v.y);
                bws[4 * c4 + 2][kk] = f2bf(v.z);
                bws[4 * c4 + 3][kk] = f2bf(v.w);
            }
            __syncthreads();
            #pragma unroll
            for (int k0 = 0; k0 < 64; k0 += 32) {
                bf16x8 af[2], bfr[2];
                #pragma unroll
                for (int m = 0; m < 2; ++m)
                    af[m] = *(const bf16x8*)&axs[m0 + m * 16 + (l & 15)][k0 + (l >> 4) * 8];
                #pragma unroll
                for (int n = 0; n < 2; ++n)
                    bfr[n] = *(const bf16x8*)&bws[np + n * 16 + (l & 15)][k0 + (l >> 4) * 8];
                #pragma unroll
                for (int m = 0; m < 2; ++m)
                    #pragma unroll
                    for (int n = 0; n < 2; ++n)
                        acc[m][n] = __builtin_amdgcn_mfma_f32_16x16x32_bf16(af[m], bfr[n], acc[m][n], 0, 0, 0);
            }
        }
        __syncthreads();   // done with LDS; reuse axs as reduction buffer
        float a1c[2], a2c[2];
        #pragma unroll
        for (int n = 0; n < 2; ++n) {
            a1c[n] = a1[h * HID + np + n * 16 + (l & 15)];
            a2c[n] = a2[h * HID + np + n * 16 + (l & 15)];
        }
        float* fred = (float*)&axs[0][0];   // [2(f)][2(wn)][64(row)]
        int wn = w & 1;
        #pragma unroll
        for (int m = 0; m < 2; ++m) {
            #pragma unroll
            for (int r = 0; r < 4; ++r) {
                int row = m0 + m * 16 + (l >> 4) * 4 + r;
                #pragma unroll
                for (int n = 0; n < 2; ++n)
                    Whb[((size_t)(n0 + row) * HEADS + h) * HID + np + n * 16 + (l & 15)] =
                        f2bf(acc[m][n][r]);
                float s1 = acc[m][0][r] * a1c[0] + acc[m][1][r] * a1c[1];
                float s2 = acc[m][0][r] * a2c[0] + acc[m][1][r] * a2c[1];
                #pragma unroll
                for (int off = 8; off; off >>= 1) {
                    s1 += __shfl_xor(s1, off);
                    s2 += __shfl_xor(s2, off);
                }
                if ((l & 15) == 0) {
                    fred[0 * 128 + wn * 64 + row] = s1;
                    fred[1 * 128 + wn * 64 + row] = s2;
                }
            }
        }
        __syncthreads();
        if (t < 64) {
            f1[(size_t)(n0 + t) * HEADS + h] = fred[t] + fred[64 + t];
            f2[(size_t)(n0 + t) * HEADS + h] = fred[128 + t] + fred[192 + t];
        }
    } else {
        // ---------------- CSR build: one block per adj row ----------------
        int g = bid / 9, r9 = bid % 9;
        int row = g * 8 + r9 - 1;               // 0..4095
        int* wcols = (int*)&axs[0][0];          // [4][MAXDEG] overlay on LDS
        int* wcnt  = (int*)&bws[0][0];          // [4]
        const float4* arow = (const float4*)(adj + (size_t)row * N_NODES);
        float4 v0 = arow[w * 256 + 0 * 64 + l];
        float4 v1 = arow[w * 256 + 1 * 64 + l];
        float4 v2 = arow[w * 256 + 2 * 64 + l];
        float4 v3 = arow[w * 256 + 3 * 64 + l];
        int base = 0;
        float4 vv[4] = {v0, v1, v2, v3};
        #pragma unroll
        for (int i = 0; i < 4; ++i) {
            float comp[4] = {vv[i].x, vv[i].y, vv[i].z, vv[i].w};
            #pragma unroll
            for (int q = 0; q < 4; ++q) {
                bool pred = comp[q] > 0.f;
                unsigned long long mask = __ballot(pred);
                if (pred) {
                    int pos = base + __popcll(mask & ((1ull << l) - 1ull));
                    if (pos < MAXDEG) wcols[w * MAXDEG + pos] = (w * 256 + i * 64 + l) * 4 + q;
                }
                base += __popcll(mask);
            }
        }
        if (l == 0) wcnt[w] = base < MAXDEG ? base : MAXDEG;
        __syncthreads();
        int c0 = wcnt[0], c1 = wcnt[1], c2 = wcnt[2], c3 = wcnt[3];
        int off = (w > 0 ? c0 : 0) + (w > 1 ? c1 : 0) + (w > 2 ? c2 : 0);
        int mycnt = wcnt[w];
        if (l < mycnt) {
            int gpos = off + l;
            if (gpos < MAXDEG) cols[row * MAXDEG + gpos] = wcols[w * MAXDEG + l];
        }
        if (t == 0) {
            int tot = c0 + c1 + c2 + c3;
            degs[row] = tot < MAXDEG ? tot : MAXDEG;
        }
    }
}

// ================= K2: attention layer 1, one block per node, all 8 heads =================
// PV gather batched 16/4/1 deep: all loads of a batch issued before any FMA.
__global__ __launch_bounds__(256) void attn1_node(const unsigned short* __restrict__ Whb,
                                                  const float* __restrict__ f1,
                                                  const float* __restrict__ f2,
                                                  const int* __restrict__ degs,
                                                  const int* __restrict__ cols,
                                                  unsigned short* __restrict__ hbufb) {
    __shared__ int cols_s[MAXDEG];
    __shared__ float p_s[HEADS][MAXDEG];
    __shared__ float inv_s[HEADS];
    int n = blockIdx.x;
    int t = threadIdx.x;
    int w = t >> 6, l = t & 63;
    int deg = degs[n];
    if (t < deg) cols_s[t] = cols[n * MAXDEG + t];
    __syncthreads();
    #pragma unroll
    for (int pass = 0; pass < 2; ++pass) {
        int h = 2 * w + pass;
        float e = -1e30f;
        if (l < deg) {
            int cj = cols_s[l];
            float v = f1[n * HEADS + h] + f2[cj * HEADS + h];
            e = v > 0.f ? v : ALPHA * v;
        }
        float m = e;
        #pragma unroll
        for (int off = 32; off; off >>= 1) m = fmaxf(m, __shfl_xor(m, off));
        float p = (l < deg) ? expf(e - m) : 0.f;
        float s = p;
        #pragma unroll
        for (int off = 32; off; off >>= 1) s += __shfl_xor(s, off);
        p_s[h][l] = p;
        if (l == 0) inv_s[h] = 1.f / s;
    }
    __syncthreads();
    int h = 2 * w + (l >> 5);
    const ushort2* whp = (const ushort2*)Whb;   // [n][256] ushort2
    float ax = 0.f, ay = 0.f;
    int j = 0;
    for (; j + 16 <= deg; j += 16) {
        ushort2 u[16]; float pj[16];
        #pragma unroll
        for (int q = 0; q < 16; ++q) u[q] = whp[(size_t)cols_s[j + q] * 256 + w * 64 + l];
        #pragma unroll
        for (int q = 0; q < 16; ++q) pj[q] = p_s[h][j + q];
        #pragma unroll
        for (int q = 0; q < 16; ++q) { ax += pj[q] * bf2f(u[q].x); ay += pj[q] * bf2f(u[q].y); }
    }
    for (; j + 4 <= deg; j += 4) {
        ushort2 u[4]; float pj[4];
        #pragma unroll
        for (int q = 0; q < 4; ++q) u[q] = whp[(size_t)cols_s[j + q] * 256 + w * 64 + l];
        #pragma unroll
        for (int q = 0; q < 4; ++q) pj[q] = p_s[h][j + q];
        #pragma unroll
        for (int q = 0; q < 4; ++q) { ax += pj[q] * bf2f(u[q].x); ay += pj[q] * bf2f(u[q].y); }
    }
    for (; j < deg; ++j) {
        ushort2 u = whp[(size_t)cols_s[j] * 256 + w * 64 + l];
        float pj = p_s[h][j];
        ax += pj * bf2f(u.x); ay += pj * bf2f(u.y);
    }
    float inv = inv_s[h];
    ushort2 o2;
    o2.x = f2bf(ax * inv);
    o2.y = f2bf(ay * inv);
    *(ushort2*)&hbufb[(size_t)n * 512 + w * 128 + l * 2] = o2;
}

// ================= K3: gemm2 (MFMA) + fused f1/f2 =================
// 32-row tiles -> 128 blocks. Full A-tile (32x512 bf16 = 2048 uint4, 8/thread) loaded
// upfront to registers, written once to LDS; Wo staged per 128-K chunk.
__global__ __launch_bounds__(256) void gemm2_f(const unsigned short* __restrict__ hbufb,
                                               const float* __restrict__ Wo,
                                               const float* __restrict__ a1,
                                               const float* __restrict__ a2,
                                               float* __restrict__ Wh2,
                                               float* __restrict__ f1,
                                               float* __restrict__ f2) {
    __shared__ __attribute__((aligned(16))) unsigned short axs[32][520];   // A [row][k] 33.3KB
    __shared__ __attribute__((aligned(16))) unsigned short bws[64][136];   // Wo^T chunk 17.4KB
    int m0 = blockIdx.x * 32;
    int t = threadIdx.x;
    int w = t >> 6, l = t & 63;
    // upfront A load: 32 rows x 512 k bf16 = 2048 uint4, 8 per thread, all independent
    uint4 areg[8];
    #pragma unroll
    for (int i = 0; i < 8; ++i) {
        int e = t + i * 256;
        int r = e >> 6, c = e & 63;
        areg[i] = *(const uint4*)&hbufb[(size_t)(m0 + r) * 512 + c * 8];
    }
    #pragma unroll
    for (int i = 0; i < 8; ++i) {
        int e = t + i * 256;
        int r = e >> 6, c = e & 63;
        *(uint4*)&axs[r][c * 8] = areg[i];
    }
    int mrow = (w & 1) * 16;          // 16-row m-tile
    int nbase = (w >> 1) * 32;        // 32-col half
    f32x4 zf = {0.f, 0.f, 0.f, 0.f};
    f32x4 acc[2] = {zf, zf};
    const float4* wo4 = (const float4*)Wo;
    for (int kc = 0; kc < HEADS * HID; kc += 128) {
        __syncthreads();   // previous MFMA done with bws (and 1st iter: axs writes visible)
        #pragma unroll
        for (int i = 0; i < 8; ++i) {      // Wo^T chunk: 128 k x 64 o
            int e = t + i * 256;
            int kk = e >> 4, c4 = e & 15;
            float4 v = wo4[(size_t)(kc + kk) * (OUT_DIM / 4) + c4];
            bws[4 * c4 + 0][kk] = f2bf(v.x);
            bws[4 * c4 + 1][kk] = f2bf(v.y);
            bws[4 * c4 + 2][kk] = f2bf(v.z);
            bws[4 * c4 + 3][kk] = f2bf(v.w);
        }
        __syncthreads();
        #pragma unroll
        for (int k0 = 0; k0 < 128; k0 += 32) {
            bf16x8 af = *(const bf16x8*)&axs[mrow + (l & 15)][kc + k0 + (l >> 4) * 8];
            #pragma unroll
            for (int n = 0; n < 2; ++n) {
                bf16x8 bfr = *(const bf16x8*)&bws[nbase + n * 16 + (l & 15)][k0 + (l >> 4) * 8];
                acc[n] = __builtin_amdgcn_mfma_f32_16x16x32_bf16(af, bfr, acc[n], 0, 0, 0);
            }
        }
    }
    float a1c[2], a2c[2];
    #pragma unroll
    for (int n = 0; n < 2; ++n) {
        a1c[n] = a1[nbase + n * 16 + (l & 15)];
        a2c[n] = a2[nbase + n * 16 + (l & 15)];
    }
    __syncthreads();                        // done with LDS; reuse axs for f-reduction
    float* fred = (float*)&axs[0][0];       // [2(f)][2(colhalf)][32(row)]
    int ch = w >> 1;
    #pragma unroll
    for (int r = 0; r < 4; ++r) {
        int row = mrow + (l >> 4) * 4 + r;  // 0..31 within block
        float s1 = 0.f, s2 = 0.f;
        #pragma unroll
        for (int n = 0; n < 2; ++n) {
            Wh2[(size_t)(m0 + row) * OUT_DIM + nbase + n * 16 + (l & 15)] = acc[n][r];
            s1 += acc[n][r] * a1c[n];
            s2 += acc[n][r] * a2c[n];
        }
        #pragma unroll
        for (int off = 8; off; off >>= 1) {
            s1 += __shfl_xor(s1, off);
            s2 += __shfl_xor(s2, off);
        }
        if ((l & 15) == 0) {
            fred[ch * 32 + row] = s1;
            fred[64 + ch * 32 + row] = s2;
        }
    }
    __syncthreads();
    if (t < 32) {
        f1[m0 + t] = fred[t] + fred[32 + t];
        f2[m0 + t] = fred[64 + t] + fred[96 + t];
    }
}

// ================= K4: attention layer 2 (+ELU), 1 wave per node, 8-deep gather =============
__global__ __launch_bounds__(256) void attn2(const float* __restrict__ Wh,
                                             const float* __restrict__ f1,
                                             const float* __restrict__ f2,
                                             const int* __restrict__ degs,
                                             const int* __restrict__ cols,
                                             float* __restrict__ out) {
    int wave = threadIdx.x >> 6;
    int lane = threadIdx.x & 63;
    int n = blockIdx.x * 4 + wave;
    if (n >= N_NODES) return;
    int deg = degs[n];
    int col = 0;
    float e = -1e30f;
    if (lane < deg) {
        col = cols[n * MAXDEG + lane];
        float v = f1[n] + f2[col];
        e = v > 0.f ? v : ALPHA * v;
    }
    float m = e;
    #pragma unroll
    for (int off = 32; off; off >>= 1) m = fmaxf(m, __shfl_xor(m, off));
    float p = (lane < deg) ? expf(e - m) : 0.f;
    float s = p;
    #pragma unroll
    for (int off = 32; off; off >>= 1) s += __shfl_xor(s, off);
    float inv = 1.f / s;
    float acc = 0.f;
    int j = 0;
    for (; j + 8 <= deg; j += 8) {
        int cj[8]; float pj[8]; float v[8];
        #pragma unroll
        for (int q = 0; q < 8; ++q) cj[q] = __shfl(col, j + q);
        #pragma unroll
        for (int q = 0; q < 8; ++q) pj[q] = __shfl(p, j + q);
        #pragma unroll
        for (int q = 0; q < 8; ++q) v[q] = Wh[(size_t)cj[q] * OUT_DIM + lane];
        #pragma unroll
        for (int q = 0; q < 8; ++q) acc += pj[q] * v[q];
    }
    for (; j < deg; ++j) {
        int cj = __shfl(col, j);
        float pj = __shfl(p, j);
        acc += pj * Wh[(size_t)cj * OUT_DIM + lane];
    }
    acc *= inv;
    acc = acc > 0.f ? acc : expf(acc) - 1.f;   // ELU
    out[(size_t)n * OUT_DIM + lane] = acc;
}

extern "C" void kernel_launch(void* const* d_in, const int* in_sizes, int n_in,
                              void* d_out, int out_size, void* d_ws, size_t ws_size,
                              hipStream_t stream) {
    const float* x    = (const float*)d_in[0];
    const float* adj  = (const float*)d_in[1];
    const float* W_h  = (const float*)d_in[2];
    const float* a1_h = (const float*)d_in[3];
    const float* a2_h = (const float*)d_in[4];
    const float* W_o  = (const float*)d_in[5];
    const float* a1_o = (const float*)d_in[6];
    const float* a2_o = (const float*)d_in[7];
    float* out = (float*)d_out;

    float* wsf  = (float*)d_ws;
    float* Wh2  = wsf;                                  // [n][64] fp32
    float* f1_1 = Wh2 + (size_t)N_NODES * OUT_DIM;      // [n][8]
    float* f2_1 = f1_1 + (size_t)N_NODES * HEADS;
    float* f1_2 = f2_1 + (size_t)N_NODES * HEADS;       // [n]
    float* f2_2 = f1_2 + N_NODES;
    int*   degs = (int*)(f2_2 + N_NODES);
    int*   csr  = degs + N_NODES;                       // [n][64]
    unsigned short* Whb   = (unsigned short*)(csr + (size_t)N_NODES * MAXDEG); // bf16 [n][h][o]
    unsigned short* hbufb = Whb + (size_t)N_NODES * HEADS * HID;               // bf16 [n][512]

    // K1: gemm1-MFMA (512 blocks, bid%9==0) interleaved with csr build (4096 blocks, 1/row)
    k1_gemm_csr<<<4608, 256, 0, stream>>>(x, W_h, a1_h, a2_h, Whb, f1_1, f2_1, adj, degs, csr);

    // K2: attention layer 1 -> hbufb bf16 [n][512]
    attn1_node<<<N_NODES, 256, 0, stream>>>(Whb, f1_1, f2_1, degs, csr, hbufb);

    // K3: layer-2 GEMM (MFMA) + fused f1/f2  (128 blocks)
    gemm2_f<<<N_NODES / 32, 256, 0, stream>>>(hbufb, W_o, a1_o, a2_o, Wh2, f1_2, f2_2);

    // K4: attention layer 2 + ELU -> d_out [n][64]
    attn2<<<N_NODES / 4, 256, 0, stream>>>(Wh2, f1_2, f2_2, degs, csr, out);
}